// Round 2
// baseline (880.215 us; speedup 1.0000x reference)
//
#include <hip/hip_runtime.h>
#include <hip/hip_bf16.h>

#define NB 256      // batch
#define D 64        // embedding dim
#define NI 10000    // items
#define HID 32

// ws layout (float offsets)
static constexpr int WS_AL = 0;                   // A_l [256][32]
static constexpr int WS_AR = 8192;                // A_r [256][32]
static constexpr int WS_N  = 16384;               // n   [256][64]
static constexpr int WS_CL = 32768;               // C_l [10000][32]
static constexpr int WS_CR = 352768;              // C_r [10000][32]
// total floats = 672768 -> 2.69 MB of d_ws

// out layout (elements, f32)
static constexpr long OUT_LIKES = 0;
static constexpr long OUT_SIM   = 2560000;
static constexpr long OUT_RATED = 2625536;
static constexpr long OUT_POP   = 5185536;

// ---------------- per-user precompute: gather eu, normalize, A = eu@W0a + b0
__global__ void k_pre(const int* __restrict__ users, const float* __restrict__ uemb,
                      const float* __restrict__ lw0, const float* __restrict__ lb0,
                      const float* __restrict__ rw0, const float* __restrict__ rb0,
                      float* __restrict__ ws) {
    int b = blockIdx.x, t = threadIdx.x;   // 256 blocks x 64 threads
    int u = users[b];
    float e = uemb[(long)u * D + t];
    float s = e * e;
    #pragma unroll
    for (int off = 32; off; off >>= 1) s += __shfl_down(s, off);
    s = __shfl(s, 0);
    ws[WS_N + b * D + t] = e * rsqrtf(fmaxf(s, 1e-12f));
    __shared__ float es[D];
    es[t] = e;
    __syncthreads();
    const float* W0 = (t < 32) ? lw0 : rw0;
    const float* bb = (t < 32) ? lb0 : rb0;
    int j = t & 31;
    float acc = bb[j];
    #pragma unroll
    for (int d = 0; d < D; ++d) acc += es[d] * W0[d * 32 + j];
    ws[((t < 32) ? WS_AL : WS_AR) + b * 32 + j] = acc;
}

// ---------------- item projections C = ie @ W0[D:] (both heads)
__global__ void k_cproj(const float* __restrict__ iemb,
                        const float* __restrict__ lw0, const float* __restrict__ rw0,
                        float* __restrict__ ws) {
    int t = threadIdx.x;               // 256 threads = 8 items x 32 j
    int i0 = blockIdx.x * 8;           // 1250 blocks
    __shared__ float xs[8][D];
    for (int idx = t; idx < 8 * D; idx += 256) {
        int it = idx >> 6, d = idx & 63; int gi = i0 + it;
        xs[it][d] = (gi < NI) ? iemb[(long)gi * D + d] : 0.f;
    }
    __syncthreads();
    int it = t >> 5, j = t & 31; int gi = i0 + it;
    float al = 0.f, ar = 0.f;
    #pragma unroll
    for (int d = 0; d < D; ++d) {
        float x = xs[it][d];
        al += x * lw0[(D + d) * 32 + j];
        ar += x * rw0[(D + d) * 32 + j];
    }
    if (gi < NI) { ws[WS_CL + gi * 32 + j] = al; ws[WS_CR + gi * 32 + j] = ar; }
}

// ---------------- popular = item_head(item_emb)
__global__ void k_pop(const float* __restrict__ iemb,
                      const float* __restrict__ pw0, const float* __restrict__ pb0,
                      const float* __restrict__ pw1, const float* __restrict__ pb1,
                      const float* __restrict__ pw2, const float* __restrict__ pb2,
                      const float* __restrict__ pw3, const float* __restrict__ pb3,
                      float* __restrict__ out) {
    int t = threadIdx.x;               // 64 threads, one item each
    int i0 = blockIdx.x * 64; int gi = i0 + t;
    __shared__ float xs[64][D + 1];
    for (int idx = t; idx < 64 * D; idx += 64) {
        int it = idx >> 6; int g2 = i0 + it;
        xs[it][t] = (g2 < NI) ? iemb[(long)g2 * D + t] : 0.f;
    }
    __syncthreads();
    float h[HID], hn[HID];
    #pragma unroll
    for (int j = 0; j < HID; ++j) h[j] = pb0[j];
    #pragma unroll
    for (int d = 0; d < D; ++d) {
        float x = xs[t][d];
        #pragma unroll
        for (int j4 = 0; j4 < 8; ++j4) {
            float4 w = *(const float4*)&pw0[d * 32 + j4 * 4];
            h[4*j4+0] += x * w.x; h[4*j4+1] += x * w.y;
            h[4*j4+2] += x * w.z; h[4*j4+3] += x * w.w;
        }
    }
    #pragma unroll
    for (int j = 0; j < HID; ++j) h[j] = fmaxf(h[j], 0.f);
    // layer 1
    #pragma unroll
    for (int j = 0; j < HID; ++j) hn[j] = pb1[j];
    #pragma unroll
    for (int k = 0; k < HID; ++k) {
        float hk = h[k];
        #pragma unroll
        for (int j4 = 0; j4 < 8; ++j4) {
            float4 w = *(const float4*)&pw1[k * 32 + j4 * 4];
            hn[4*j4+0] += hk * w.x; hn[4*j4+1] += hk * w.y;
            hn[4*j4+2] += hk * w.z; hn[4*j4+3] += hk * w.w;
        }
    }
    #pragma unroll
    for (int j = 0; j < HID; ++j) h[j] = fmaxf(hn[j], 0.f);
    // layer 2
    #pragma unroll
    for (int j = 0; j < HID; ++j) hn[j] = pb2[j];
    #pragma unroll
    for (int k = 0; k < HID; ++k) {
        float hk = h[k];
        #pragma unroll
        for (int j4 = 0; j4 < 8; ++j4) {
            float4 w = *(const float4*)&pw2[k * 32 + j4 * 4];
            hn[4*j4+0] += hk * w.x; hn[4*j4+1] += hk * w.y;
            hn[4*j4+2] += hk * w.z; hn[4*j4+3] += hk * w.w;
        }
    }
    float acc = pb3[0];
    #pragma unroll
    for (int j = 0; j < HID; ++j) acc += fmaxf(hn[j], 0.f) * pw3[j];
    float o = 1.f / (1.f + __expf(-acc));
    if (gi < NI) out[gi] = o;
}

// ---------------- the big one: pair head over (b,i)
__global__ __launch_bounds__(256) void k_pairs(
        const float* __restrict__ ws,
        const float* __restrict__ W1g, const float* __restrict__ b1g,
        const float* __restrict__ W2g, const float* __restrict__ b2g,
        const float* __restrict__ w3g, const float* __restrict__ b3g,
        int a_off, int c_off, float* __restrict__ outp) {
    __shared__ float W1s[1024], W2s[1024], w3s[32], b1s[32], b2s[32], As[128];
    __shared__ float Cs[64 * 33];
    __shared__ float b3s;
    int t = threadIdx.x;
    int i0 = blockIdx.x * 64, b0 = blockIdx.y * 4;
    for (int idx = t; idx < 1024; idx += 256) { W1s[idx] = W1g[idx]; W2s[idx] = W2g[idx]; }
    if (t < 32) { w3s[t] = w3g[t]; b1s[t] = b1g[t]; b2s[t] = b2g[t]; }
    if (t == 0) b3s = b3g[0];
    if (t < 128) As[t] = ws[a_off + (b0 + (t >> 5)) * 32 + (t & 31)];
    for (int idx = t; idx < 2048; idx += 256) {
        int r = idx >> 5, c = idx & 31; int gi = i0 + r;
        Cs[r * 33 + c] = (gi < NI) ? ws[c_off + gi * 32 + c] : 0.f;
    }
    __syncthreads();
    int bi = t >> 6, ii = t & 63;
    float h[32], tn[32];
    #pragma unroll
    for (int j = 0; j < 32; ++j) h[j] = fmaxf(As[bi * 32 + j] + Cs[ii * 33 + j], 0.f);
    // layer 1 (LDS reads are wave-uniform -> broadcast)
    #pragma unroll
    for (int j = 0; j < 32; ++j) tn[j] = b1s[j];
    #pragma unroll
    for (int k = 0; k < 32; ++k) {
        float hk = h[k];
        #pragma unroll
        for (int j4 = 0; j4 < 8; ++j4) {
            float4 w = *(const float4*)&W1s[k * 32 + j4 * 4];
            tn[4*j4+0] += hk * w.x; tn[4*j4+1] += hk * w.y;
            tn[4*j4+2] += hk * w.z; tn[4*j4+3] += hk * w.w;
        }
    }
    #pragma unroll
    for (int j = 0; j < 32; ++j) h[j] = fmaxf(tn[j], 0.f);
    // layer 2
    #pragma unroll
    for (int j = 0; j < 32; ++j) tn[j] = b2s[j];
    #pragma unroll
    for (int k = 0; k < 32; ++k) {
        float hk = h[k];
        #pragma unroll
        for (int j4 = 0; j4 < 8; ++j4) {
            float4 w = *(const float4*)&W2s[k * 32 + j4 * 4];
            tn[4*j4+0] += hk * w.x; tn[4*j4+1] += hk * w.y;
            tn[4*j4+2] += hk * w.z; tn[4*j4+3] += hk * w.w;
        }
    }
    float acc = b3s;
    #pragma unroll
    for (int j = 0; j < 32; ++j) acc += fmaxf(tn[j], 0.f) * w3s[j];
    float o = 1.f / (1.f + __expf(-acc));
    int gi = i0 + ii;
    if (gi < NI) outp[(long)(b0 + bi) * NI + gi] = o;
}

// ---------------- user_sim = (1 - cos)/2
__global__ void k_sim(const float* __restrict__ ws, float* __restrict__ out) {
    int b = blockIdx.x, j = threadIdx.x;    // 256 x 256
    __shared__ float nb[D];
    if (j < D) nb[j] = ws[WS_N + b * D + j];
    __syncthreads();
    const float* nj = &ws[WS_N + j * D];
    float acc = 0.f;
    #pragma unroll
    for (int d = 0; d < D; ++d) acc += nb[d] * nj[d];
    out[OUT_SIM + (long)b * 256 + j] = (1.f - acc) * 0.5f;
}

extern "C" void kernel_launch(void* const* d_in, const int* in_sizes, int n_in,
                              void* d_out, int out_size, void* d_ws, size_t ws_size,
                              hipStream_t stream) {
    const int*   users = (const int*)d_in[0];
    const float* uemb  = (const float*)d_in[1];
    const float* iemb  = (const float*)d_in[2];
    const float *lw0 = (const float*)d_in[3],  *lb0 = (const float*)d_in[4];
    const float *lw1 = (const float*)d_in[5],  *lb1 = (const float*)d_in[6];
    const float *lw2 = (const float*)d_in[7],  *lb2 = (const float*)d_in[8];
    const float *lw3 = (const float*)d_in[9],  *lb3 = (const float*)d_in[10];
    const float *rw0 = (const float*)d_in[11], *rb0 = (const float*)d_in[12];
    const float *rw1 = (const float*)d_in[13], *rb1 = (const float*)d_in[14];
    const float *rw2 = (const float*)d_in[15], *rb2 = (const float*)d_in[16];
    const float *rw3 = (const float*)d_in[17], *rb3 = (const float*)d_in[18];
    const float *pw0 = (const float*)d_in[19], *pb0 = (const float*)d_in[20];
    const float *pw1 = (const float*)d_in[21], *pb1 = (const float*)d_in[22];
    const float *pw2 = (const float*)d_in[23], *pb2 = (const float*)d_in[24];
    const float *pw3 = (const float*)d_in[25], *pb3 = (const float*)d_in[26];
    float* ws = (float*)d_ws;
    float* out = (float*)d_out;

    k_pre<<<NB, 64, 0, stream>>>(users, uemb, lw0, lb0, rw0, rb0, ws);
    k_cproj<<<1250, 256, 0, stream>>>(iemb, lw0, rw0, ws);
    k_pop<<<157, 64, 0, stream>>>(iemb, pw0, pb0, pw1, pb1, pw2, pb2, pw3, pb3,
                                  out + OUT_POP);
    dim3 g(157, 64);
    k_pairs<<<g, 256, 0, stream>>>(ws, lw1, lb1, lw2, lb2, lw3, lb3,
                                   WS_AL, WS_CL, out + OUT_LIKES);
    k_pairs<<<g, 256, 0, stream>>>(ws, rw1, rb1, rw2, rb2, rw3, rb3,
                                   WS_AR, WS_CR, out + OUT_RATED);
    k_sim<<<256, 256, 0, stream>>>(ws, out);
}

// Round 3
// 119.064 us; speedup vs baseline: 7.3928x; 7.3928x over previous
//
#include <hip/hip_runtime.h>
#include <hip/hip_bf16.h>

#define NB 256      // batch
#define D 64        // embedding dim
#define NI 10000    // items

typedef __attribute__((ext_vector_type(8))) short bf16x8;
typedef __attribute__((ext_vector_type(4))) float f32x4;

// ws layout (float offsets)
static constexpr int WS_AL = 0;                   // A_l [256][32]
static constexpr int WS_AR = 8192;                // A_r [256][32]
static constexpr int WS_N  = 16384;               // n   [256][64]
static constexpr int WS_CL = 32768;               // C_l [10000][32]
static constexpr int WS_CR = 352768;              // C_r [10000][32]

// out layout (elements, f32)
static constexpr long OUT_LIKES = 0;
static constexpr long OUT_SIM   = 2560000;
static constexpr long OUT_RATED = 2625536;
static constexpr long OUT_POP   = 5185536;

__device__ __forceinline__ short f2bf(float f) {
    __hip_bfloat16 h = __float2bfloat16(f);
    return *reinterpret_cast<short*>(&h);
}

// ================= prep: user gather+norm+A-proj | item C-proj | popular head
__global__ __launch_bounds__(256) void k_prep(
        const int* __restrict__ users, const float* __restrict__ uemb,
        const float* __restrict__ iemb,
        const float* __restrict__ lw0, const float* __restrict__ lb0,
        const float* __restrict__ rw0, const float* __restrict__ rb0,
        const float* __restrict__ pw0, const float* __restrict__ pb0,
        const float* __restrict__ pw1, const float* __restrict__ pb1,
        const float* __restrict__ pw2, const float* __restrict__ pb2,
        const float* __restrict__ pw3, const float* __restrict__ pb3,
        float* __restrict__ ws, float* __restrict__ out) {
    int bx = blockIdx.x, t = threadIdx.x;
    if (bx < 64) {
        // ---- user precompute: 4 users per block, one wave each
        __shared__ float es[4][D];
        int ug = t >> 6, tt = t & 63;
        int b = bx * 4 + ug;
        int u = users[b];
        float e = uemb[(long)u * D + tt];
        float s = e * e;
        #pragma unroll
        for (int off = 32; off; off >>= 1) s += __shfl_down(s, off);
        s = __shfl(s, 0);
        ws[WS_N + b * D + tt] = e * rsqrtf(fmaxf(s, 1e-12f));
        es[ug][tt] = e;
        __syncthreads();
        const float* W0 = (tt < 32) ? lw0 : rw0;
        const float* bb = (tt < 32) ? lb0 : rb0;
        int j = tt & 31;
        float acc = bb[j];
        #pragma unroll
        for (int d = 0; d < D; ++d) acc += es[ug][d] * W0[d * 32 + j];
        ws[((tt < 32) ? WS_AL : WS_AR) + b * 32 + j] = acc;
    } else if (bx < 64 + 1250) {
        // ---- item projections C = ie @ W0[D:] for both heads
        int i0 = (bx - 64) * 8;
        __shared__ float xs[8][D];
        for (int idx = t; idx < 8 * D; idx += 256) {
            int it = idx >> 6, d = idx & 63; int gi = i0 + it;
            xs[it][d] = (gi < NI) ? iemb[(long)gi * D + d] : 0.f;
        }
        __syncthreads();
        int it = t >> 5, j = t & 31; int gi = i0 + it;
        float al = 0.f, ar = 0.f;
        #pragma unroll
        for (int d = 0; d < D; ++d) {
            float x = xs[it][d];
            al += x * lw0[(D + d) * 32 + j];
            ar += x * rw0[(D + d) * 32 + j];
        }
        if (gi < NI) { ws[WS_CL + gi * 32 + j] = al; ws[WS_CR + gi * 32 + j] = ar; }
    } else {
        // ---- popular = item_head(item_emb), one item per thread
        int gi = (bx - 1314) * 256 + t;
        if (gi >= NI) return;
        float h[32], hn[32];
        #pragma unroll
        for (int j = 0; j < 32; ++j) h[j] = pb0[j];
        const float4* xr = (const float4*)(iemb + (long)gi * D);
        #pragma unroll
        for (int d4 = 0; d4 < 16; ++d4) {
            float4 xv = xr[d4];
            float xa[4] = {xv.x, xv.y, xv.z, xv.w};
            #pragma unroll
            for (int q = 0; q < 4; ++q) {
                float x = xa[q]; int d = d4 * 4 + q;
                #pragma unroll
                for (int j4 = 0; j4 < 8; ++j4) {
                    float4 w = *(const float4*)&pw0[d * 32 + j4 * 4];
                    h[4*j4+0] += x * w.x; h[4*j4+1] += x * w.y;
                    h[4*j4+2] += x * w.z; h[4*j4+3] += x * w.w;
                }
            }
        }
        #pragma unroll
        for (int j = 0; j < 32; ++j) h[j] = fmaxf(h[j], 0.f);
        #pragma unroll
        for (int j = 0; j < 32; ++j) hn[j] = pb1[j];
        #pragma unroll
        for (int k = 0; k < 32; ++k) {
            float hk = h[k];
            #pragma unroll
            for (int j4 = 0; j4 < 8; ++j4) {
                float4 w = *(const float4*)&pw1[k * 32 + j4 * 4];
                hn[4*j4+0] += hk * w.x; hn[4*j4+1] += hk * w.y;
                hn[4*j4+2] += hk * w.z; hn[4*j4+3] += hk * w.w;
            }
        }
        #pragma unroll
        for (int j = 0; j < 32; ++j) h[j] = fmaxf(hn[j], 0.f);
        #pragma unroll
        for (int j = 0; j < 32; ++j) hn[j] = pb2[j];
        #pragma unroll
        for (int k = 0; k < 32; ++k) {
            float hk = h[k];
            #pragma unroll
            for (int j4 = 0; j4 < 8; ++j4) {
                float4 w = *(const float4*)&pw2[k * 32 + j4 * 4];
                hn[4*j4+0] += hk * w.x; hn[4*j4+1] += hk * w.y;
                hn[4*j4+2] += hk * w.z; hn[4*j4+3] += hk * w.w;
            }
        }
        float acc = pb3[0];
        #pragma unroll
        for (int j = 0; j < 32; ++j) acc += fmaxf(hn[j], 0.f) * pw3[j];
        out[OUT_POP + gi] = 1.f / (1.f + __expf(-acc));
    }
}

// ================= main: MFMA pair heads (likes+rated) + user_sim
// Transposed formulation: D = W^T @ X^T per layer.
//   16x16x32 bf16 MFMA, C/D layout: col = lane&15 (= pair p), row = (lane>>4)*4+reg.
//   Self-consistent k conventions (A and B built by us, so any shared convention works):
//     L1: k1 = 8*g + i   (contiguous -> float4 loads of X inputs)
//     L2: k2 = 4*g + (i&3) + 16*(i>>2)  (matches L1's C/D output in-lane -> zero exchange)
__global__ __launch_bounds__(256) void k_main(
        const float* __restrict__ ws,
        const float* __restrict__ lw1, const float* __restrict__ lb1,
        const float* __restrict__ lw2, const float* __restrict__ lb2,
        const float* __restrict__ lw3, const float* __restrict__ lb3,
        const float* __restrict__ rw1, const float* __restrict__ rb1,
        const float* __restrict__ rw2, const float* __restrict__ rb2,
        const float* __restrict__ rw3, const float* __restrict__ rb3,
        float* __restrict__ out) {
    __shared__ float nb[D];
    int bx = blockIdx.x, t = threadIdx.x;
    if (bx < 1250) {
        int head = (bx >= 625);
        int i0 = (head ? bx - 625 : bx) * 16;
        const float* W1 = head ? rw1 : lw1; const float* B1 = head ? rb1 : lb1;
        const float* W2 = head ? rw2 : lw2; const float* B2 = head ? rb2 : lb2;
        const float* w3 = head ? rw3 : lw3; const float* b3 = head ? rb3 : lb3;
        int a_off = head ? WS_AR : WS_AL;
        int c_off = head ? WS_CR : WS_CL;
        float* ob = out + (head ? OUT_RATED : OUT_LIKES);

        int lane = t & 63, wv = t >> 6;
        int p = lane & 15, g = lane >> 4;

        // weight fragments (A operands = W^T), gathered once
        bf16x8 w1f0, w1f1, w2f0, w2f1;
        #pragma unroll
        for (int i = 0; i < 8; ++i) {
            int k1 = 8 * g + i;
            w1f0[i] = f2bf(W1[k1 * 32 + p]);
            w1f1[i] = f2bf(W1[k1 * 32 + p + 16]);
            int k2 = 4 * g + (i & 3) + 16 * (i >> 2);
            w2f0[i] = f2bf(W2[k2 * 32 + p]);
            w2f1[i] = f2bf(W2[k2 * 32 + p + 16]);
        }
        float4 b1v0 = *(const float4*)&B1[4 * g];
        float4 b1v1 = *(const float4*)&B1[16 + 4 * g];
        float4 b2v0 = *(const float4*)&B2[4 * g];
        float4 b2v1 = *(const float4*)&B2[16 + 4 * g];
        float4 w3v0 = *(const float4*)&w3[4 * g];
        float4 w3v1 = *(const float4*)&w3[16 + 4 * g];
        float b3s = b3[0];

        // item projection fragment (fixed per wave)
        const float* cb = ws + c_off + (i0 + p) * 32 + 8 * g;
        float4 c0 = *(const float4*)cb;
        float4 c1 = *(const float4*)(cb + 4);

        // user loop: wave wv handles users [wv*64, wv*64+64)
        const float* ab = ws + a_off + 8 * g;
        float4 a0 = *(const float4*)&ab[(wv * 64) * 32];
        float4 a1 = *(const float4*)&ab[(wv * 64) * 32 + 4];

        for (int u = 0; u < 64; ++u) {
            int b = wv * 64 + u;
            float4 na0 = a0, na1 = a1;
            if (u < 63) {
                na0 = *(const float4*)&ab[(b + 1) * 32];
                na1 = *(const float4*)&ab[(b + 1) * 32 + 4];
            }
            // X fragment: x[p][k1] = relu(A[b][k1] + C[i0+p][k1])
            bf16x8 xb;
            xb[0] = f2bf(fmaxf(a0.x + c0.x, 0.f));
            xb[1] = f2bf(fmaxf(a0.y + c0.y, 0.f));
            xb[2] = f2bf(fmaxf(a0.z + c0.z, 0.f));
            xb[3] = f2bf(fmaxf(a0.w + c0.w, 0.f));
            xb[4] = f2bf(fmaxf(a1.x + c1.x, 0.f));
            xb[5] = f2bf(fmaxf(a1.y + c1.y, 0.f));
            xb[6] = f2bf(fmaxf(a1.z + c1.z, 0.f));
            xb[7] = f2bf(fmaxf(a1.w + c1.w, 0.f));
            // layer 1: C1^T = W1^T @ X^T  (+ bias via C-in)
            f32x4 acc0 = {b1v0.x, b1v0.y, b1v0.z, b1v0.w};
            f32x4 acc1 = {b1v1.x, b1v1.y, b1v1.z, b1v1.w};
            acc0 = __builtin_amdgcn_mfma_f32_16x16x32_bf16(w1f0, xb, acc0, 0, 0, 0);
            acc1 = __builtin_amdgcn_mfma_f32_16x16x32_bf16(w1f1, xb, acc1, 0, 0, 0);
            // relu + pack: lane's own C1 rows ARE its p-column under k2 convention
            bf16x8 hb;
            hb[0] = f2bf(fmaxf(acc0[0], 0.f));
            hb[1] = f2bf(fmaxf(acc0[1], 0.f));
            hb[2] = f2bf(fmaxf(acc0[2], 0.f));
            hb[3] = f2bf(fmaxf(acc0[3], 0.f));
            hb[4] = f2bf(fmaxf(acc1[0], 0.f));
            hb[5] = f2bf(fmaxf(acc1[1], 0.f));
            hb[6] = f2bf(fmaxf(acc1[2], 0.f));
            hb[7] = f2bf(fmaxf(acc1[3], 0.f));
            // layer 2
            f32x4 d0v = {b2v0.x, b2v0.y, b2v0.z, b2v0.w};
            f32x4 d1v = {b2v1.x, b2v1.y, b2v1.z, b2v1.w};
            d0v = __builtin_amdgcn_mfma_f32_16x16x32_bf16(w2f0, hb, d0v, 0, 0, 0);
            d1v = __builtin_amdgcn_mfma_f32_16x16x32_bf16(w2f1, hb, d1v, 0, 0, 0);
            // final dot + reduce across the 4 lane-groups
            float red = fmaxf(d0v[0], 0.f) * w3v0.x + fmaxf(d0v[1], 0.f) * w3v0.y
                      + fmaxf(d0v[2], 0.f) * w3v0.z + fmaxf(d0v[3], 0.f) * w3v0.w
                      + fmaxf(d1v[0], 0.f) * w3v1.x + fmaxf(d1v[1], 0.f) * w3v1.y
                      + fmaxf(d1v[2], 0.f) * w3v1.z + fmaxf(d1v[3], 0.f) * w3v1.w;
            red += __shfl_xor(red, 16);
            red += __shfl_xor(red, 32);
            if (lane < 16) {
                float o = 1.f / (1.f + __expf(-(red + b3s)));
                ob[(long)b * NI + i0 + p] = o;
            }
            a0 = na0; a1 = na1;
        }
    } else {
        // ---- user_sim
        int b = bx - 1250;
        if (t < D) nb[t] = ws[WS_N + b * D + t];
        __syncthreads();
        const float* nj = ws + WS_N + t * D;
        float acc = 0.f;
        #pragma unroll
        for (int d = 0; d < D; ++d) acc += nb[d] * nj[d];
        out[OUT_SIM + (long)b * 256 + t] = (1.f - acc) * 0.5f;
    }
}

extern "C" void kernel_launch(void* const* d_in, const int* in_sizes, int n_in,
                              void* d_out, int out_size, void* d_ws, size_t ws_size,
                              hipStream_t stream) {
    const int*   users = (const int*)d_in[0];
    const float* uemb  = (const float*)d_in[1];
    const float* iemb  = (const float*)d_in[2];
    const float *lw0 = (const float*)d_in[3],  *lb0 = (const float*)d_in[4];
    const float *lw1 = (const float*)d_in[5],  *lb1 = (const float*)d_in[6];
    const float *lw2 = (const float*)d_in[7],  *lb2 = (const float*)d_in[8];
    const float *lw3 = (const float*)d_in[9],  *lb3 = (const float*)d_in[10];
    const float *rw0 = (const float*)d_in[11], *rb0 = (const float*)d_in[12];
    const float *rw1 = (const float*)d_in[13], *rb1 = (const float*)d_in[14];
    const float *rw2 = (const float*)d_in[15], *rb2 = (const float*)d_in[16];
    const float *rw3 = (const float*)d_in[17], *rb3 = (const float*)d_in[18];
    const float *pw0 = (const float*)d_in[19], *pb0 = (const float*)d_in[20];
    const float *pw1 = (const float*)d_in[21], *pb1 = (const float*)d_in[22];
    const float *pw2 = (const float*)d_in[23], *pb2 = (const float*)d_in[24];
    const float *pw3 = (const float*)d_in[25], *pb3 = (const float*)d_in[26];
    float* ws = (float*)d_ws;
    float* out = (float*)d_out;

    k_prep<<<1354, 256, 0, stream>>>(users, uemb, iemb, lw0, lb0, rw0, rb0,
                                     pw0, pb0, pw1, pb1, pw2, pb2, pw3, pb3,
                                     ws, out);
    k_main<<<1506, 256, 0, stream>>>(ws,
                                     lw1, lb1, lw2, lb2, lw3, lb3,
                                     rw1, rb1, rw2, rb2, rw3, rb3,
                                     out);
}

// Round 4
// 117.836 us; speedup vs baseline: 7.4698x; 1.0104x over previous
//
#include <hip/hip_runtime.h>
#include <hip/hip_bf16.h>

#define NB 256      // batch
#define D 64        // embedding dim
#define NI 10000    // items

typedef __attribute__((ext_vector_type(8))) short bf16x8;
typedef __attribute__((ext_vector_type(16))) float f32x16;

union PK8 { unsigned u[4]; bf16x8 v; };

// ws layout (float offsets)
static constexpr int WS_AL = 0;                   // A_l [256][32]
static constexpr int WS_AR = 8192;                // A_r [256][32]
static constexpr int WS_N  = 16384;               // n   [256][64]
static constexpr int WS_CL = 32768;               // C_l [10000][32]
static constexpr int WS_CR = 352768;              // C_r [10000][32]

// out layout (elements, f32)
static constexpr long OUT_LIKES = 0;
static constexpr long OUT_SIM   = 2560000;
static constexpr long OUT_RATED = 2625536;
static constexpr long OUT_POP   = 5185536;

__device__ __forceinline__ short f2bf(float f) {
    __hip_bfloat16 h = __float2bfloat16(f);
    return *reinterpret_cast<short*>(&h);
}

// 2 f32 -> packed 2x bf16 (RNE) in one instruction (guide §T12: no builtin on gfx950)
__device__ __forceinline__ unsigned pkbf(float a, float b) {
    unsigned r;
    asm("v_cvt_pk_bf16_f32 %0, %1, %2" : "=v"(r) : "v"(a), "v"(b));
    return r;
}

__device__ __forceinline__ float relu(float x) { return fmaxf(x, 0.f); }

// ================= prep: user gather+norm+A-proj | item C-proj | popular head
__global__ __launch_bounds__(256) void k_prep(
        const int* __restrict__ users, const float* __restrict__ uemb,
        const float* __restrict__ iemb,
        const float* __restrict__ lw0, const float* __restrict__ lb0,
        const float* __restrict__ rw0, const float* __restrict__ rb0,
        const float* __restrict__ pw0, const float* __restrict__ pb0,
        const float* __restrict__ pw1, const float* __restrict__ pb1,
        const float* __restrict__ pw2, const float* __restrict__ pb2,
        const float* __restrict__ pw3, const float* __restrict__ pb3,
        float* __restrict__ ws, float* __restrict__ out) {
    int bx = blockIdx.x, t = threadIdx.x;
    if (bx < 64) {
        // ---- user precompute: 4 users per block, one wave each
        __shared__ float es[4][D];
        int ug = t >> 6, tt = t & 63;
        int b = bx * 4 + ug;
        int u = users[b];
        float e = uemb[(long)u * D + tt];
        float s = e * e;
        #pragma unroll
        for (int off = 32; off; off >>= 1) s += __shfl_down(s, off);
        s = __shfl(s, 0);
        ws[WS_N + b * D + tt] = e * rsqrtf(fmaxf(s, 1e-12f));
        es[ug][tt] = e;
        __syncthreads();
        const float* W0 = (tt < 32) ? lw0 : rw0;
        const float* bb = (tt < 32) ? lb0 : rb0;
        int j = tt & 31;
        float acc = bb[j];
        #pragma unroll
        for (int d = 0; d < D; ++d) acc += es[ug][d] * W0[d * 32 + j];
        ws[((tt < 32) ? WS_AL : WS_AR) + b * 32 + j] = acc;
    } else if (bx < 64 + 1250) {
        // ---- item projections C = ie @ W0[D:] for both heads
        int i0 = (bx - 64) * 8;
        __shared__ float xs[8][D];
        for (int idx = t; idx < 8 * D; idx += 256) {
            int it = idx >> 6, d = idx & 63; int gi = i0 + it;
            xs[it][d] = (gi < NI) ? iemb[(long)gi * D + d] : 0.f;
        }
        __syncthreads();
        int it = t >> 5, j = t & 31; int gi = i0 + it;
        float al = 0.f, ar = 0.f;
        #pragma unroll
        for (int d = 0; d < D; ++d) {
            float x = xs[it][d];
            al += x * lw0[(D + d) * 32 + j];
            ar += x * rw0[(D + d) * 32 + j];
        }
        if (gi < NI) { ws[WS_CL + gi * 32 + j] = al; ws[WS_CR + gi * 32 + j] = ar; }
    } else {
        // ---- popular = item_head(item_emb), one item per thread
        int gi = (bx - 1314) * 256 + t;
        if (gi >= NI) return;
        float h[32], hn[32];
        #pragma unroll
        for (int j = 0; j < 32; ++j) h[j] = pb0[j];
        const float4* xr = (const float4*)(iemb + (long)gi * D);
        #pragma unroll
        for (int d4 = 0; d4 < 16; ++d4) {
            float4 xv = xr[d4];
            float xa[4] = {xv.x, xv.y, xv.z, xv.w};
            #pragma unroll
            for (int q = 0; q < 4; ++q) {
                float x = xa[q]; int d = d4 * 4 + q;
                #pragma unroll
                for (int j4 = 0; j4 < 8; ++j4) {
                    float4 w = *(const float4*)&pw0[d * 32 + j4 * 4];
                    h[4*j4+0] += x * w.x; h[4*j4+1] += x * w.y;
                    h[4*j4+2] += x * w.z; h[4*j4+3] += x * w.w;
                }
            }
        }
        #pragma unroll
        for (int j = 0; j < 32; ++j) h[j] = fmaxf(h[j], 0.f);
        #pragma unroll
        for (int j = 0; j < 32; ++j) hn[j] = pb1[j];
        #pragma unroll
        for (int k = 0; k < 32; ++k) {
            float hk = h[k];
            #pragma unroll
            for (int j4 = 0; j4 < 8; ++j4) {
                float4 w = *(const float4*)&pw1[k * 32 + j4 * 4];
                hn[4*j4+0] += hk * w.x; hn[4*j4+1] += hk * w.y;
                hn[4*j4+2] += hk * w.z; hn[4*j4+3] += hk * w.w;
            }
        }
        #pragma unroll
        for (int j = 0; j < 32; ++j) h[j] = fmaxf(hn[j], 0.f);
        #pragma unroll
        for (int j = 0; j < 32; ++j) hn[j] = pb2[j];
        #pragma unroll
        for (int k = 0; k < 32; ++k) {
            float hk = h[k];
            #pragma unroll
            for (int j4 = 0; j4 < 8; ++j4) {
                float4 w = *(const float4*)&pw2[k * 32 + j4 * 4];
                hn[4*j4+0] += hk * w.x; hn[4*j4+1] += hk * w.y;
                hn[4*j4+2] += hk * w.z; hn[4*j4+3] += hk * w.w;
            }
        }
        float acc = pb3[0];
        #pragma unroll
        for (int j = 0; j < 32; ++j) acc += fmaxf(hn[j], 0.f) * pw3[j];
        out[OUT_POP + gi] = 1.f / (1.f + __expf(-acc));
    }
}

// ================= main: MFMA pair heads (likes+rated) + user_sim
// 32x32x16 bf16, transposed: D = W^T @ X^T.
//   C/D layout (verified m74/m101): col = lane&31 (pair), row = (reg&3)+8*(reg>>2)+4*(lane>>5).
//   Self-consistent k conventions (we build BOTH operands; square A/B layouts symmetric):
//     L1 (K=32, 2 MFMAs): kappa1(i,hi,m) = 8*hi + i + 16*m   -> contiguous float4 loads
//     L2 (K=32, 2 MFMAs): kappa2(i,hi,m) = (i&3)+8*(i>>2)+4*hi+16*m -> L1's C/D feeds B in-lane
__global__ __launch_bounds__(256) void k_main(
        const float* __restrict__ ws,
        const float* __restrict__ lw1, const float* __restrict__ lb1,
        const float* __restrict__ lw2, const float* __restrict__ lb2,
        const float* __restrict__ lw3, const float* __restrict__ lb3,
        const float* __restrict__ rw1, const float* __restrict__ rb1,
        const float* __restrict__ rw2, const float* __restrict__ rb2,
        const float* __restrict__ rw3, const float* __restrict__ rb3,
        float* __restrict__ out) {
    __shared__ float nb[D];
    int bx = blockIdx.x, t = threadIdx.x;
    if (bx < 1252) {
        int head = bx & 1;
        int ug = (bx >> 1) & 1;
        int ib = bx >> 2;                 // [0, 313)
        int i0 = ib * 32;
        const float* W1 = head ? rw1 : lw1; const float* B1 = head ? rb1 : lb1;
        const float* W2 = head ? rw2 : lw2; const float* B2 = head ? rb2 : lb2;
        const float* w3 = head ? rw3 : lw3; const float* b3 = head ? rb3 : lb3;
        int a_off = head ? WS_AR : WS_AL;
        int c_off = head ? WS_CR : WS_CL;
        float* ob = out + (head ? OUT_RATED : OUT_LIKES);

        int lane = t & 63, wv = t >> 6;
        int pr = lane & 31, hi = lane >> 5;
        int u0 = ug * 128 + wv * 32;

        // ---- weight fragments (A operands = W^T), m = pr (output feature)
        PK8 w1a, w1b, w2a, w2b;
        #pragma unroll
        for (int j = 0; j < 4; ++j) {
            int k0 = 8 * hi + 2 * j;
            w1a.u[j] = pkbf(W1[k0 * 32 + pr],        W1[(k0 + 1) * 32 + pr]);
            w1b.u[j] = pkbf(W1[(16 + k0) * 32 + pr], W1[(17 + k0) * 32 + pr]);
        }
        #pragma unroll
        for (int j = 0; j < 4; ++j) {
            // kappa2 feature pairs per word: {(0,1),(2,3),(8,9),(10,11)} + 4*hi (+16 for MFMA1)
            int fa = ((2 * j) & 3) + 8 * ((2 * j) >> 2) + 4 * hi;
            int fb = ((2 * j + 1) & 3) + 8 * ((2 * j + 1) >> 2) + 4 * hi;
            w2a.u[j] = pkbf(W2[fa * 32 + pr],        W2[fb * 32 + pr]);
            w2b.u[j] = pkbf(W2[(fa + 16) * 32 + pr], W2[(fb + 16) * 32 + pr]);
        }
        // bias / w3 gathers in C/D reg order: reg r -> feature (r&3)+8*(r>>2)+4*hi
        f32x16 binit1, binit2, w3v;
        #pragma unroll
        for (int r = 0; r < 16; ++r) {
            int f = (r & 3) + 8 * (r >> 2) + 4 * hi;
            binit1[r] = B1[f]; binit2[r] = B2[f]; w3v[r] = w3[f];
        }
        float b3s = b3[0];

        // ---- item projection values (fixed per block): C[pr][k] for k in kappa1 slots
        int crow = i0 + pr; if (crow > NI - 1) crow = NI - 1;
        const float* cp = ws + c_off + (long)crow * 32 + 8 * hi;
        float4 c0 = *(const float4*)cp;
        float4 c1 = *(const float4*)(cp + 4);
        float4 c2 = *(const float4*)(cp + 16);
        float4 c3 = *(const float4*)(cp + 20);

        bool valid = (hi == 0) && (i0 + pr < NI);
        float* op = ob + (long)u0 * NI + i0 + pr;
        const float* ap = ws + a_off + 8 * hi + u0 * 32;

        for (int u = 0; u < 32; ++u) {
            float4 ax0 = *(const float4*)ap;
            float4 ax1 = *(const float4*)(ap + 4);
            float4 ax2 = *(const float4*)(ap + 16);
            float4 ax3 = *(const float4*)(ap + 20);
            // X fragment: x[pr][k] = relu(A[b][k] + C[pr][k])
            PK8 xb0, xb1;
            xb0.u[0] = pkbf(relu(ax0.x + c0.x), relu(ax0.y + c0.y));
            xb0.u[1] = pkbf(relu(ax0.z + c0.z), relu(ax0.w + c0.w));
            xb0.u[2] = pkbf(relu(ax1.x + c1.x), relu(ax1.y + c1.y));
            xb0.u[3] = pkbf(relu(ax1.z + c1.z), relu(ax1.w + c1.w));
            xb1.u[0] = pkbf(relu(ax2.x + c2.x), relu(ax2.y + c2.y));
            xb1.u[1] = pkbf(relu(ax2.z + c2.z), relu(ax2.w + c2.w));
            xb1.u[2] = pkbf(relu(ax3.x + c3.x), relu(ax3.y + c3.y));
            xb1.u[3] = pkbf(relu(ax3.z + c3.z), relu(ax3.w + c3.w));
            // layer 1
            f32x16 acc = binit1;
            acc = __builtin_amdgcn_mfma_f32_32x32x16_bf16(w1a.v, xb0.v, acc, 0, 0, 0);
            acc = __builtin_amdgcn_mfma_f32_32x32x16_bf16(w1b.v, xb1.v, acc, 0, 0, 0);
            // relu + pack: acc reg r holds feature kappa2-slot r (by construction)
            PK8 hb0, hb1;
            #pragma unroll
            for (int j = 0; j < 4; ++j) {
                hb0.u[j] = pkbf(relu(acc[2 * j]),     relu(acc[2 * j + 1]));
                hb1.u[j] = pkbf(relu(acc[8 + 2 * j]), relu(acc[9 + 2 * j]));
            }
            // layer 2
            f32x16 acc2 = binit2;
            acc2 = __builtin_amdgcn_mfma_f32_32x32x16_bf16(w2a.v, hb0.v, acc2, 0, 0, 0);
            acc2 = __builtin_amdgcn_mfma_f32_32x32x16_bf16(w2b.v, hb1.v, acc2, 0, 0, 0);
            // final dot (each lane holds 16 of 32 features for its pair; other half in lane^32)
            float r0 = 0.f, r1 = 0.f, r2 = 0.f, r3 = 0.f;
            #pragma unroll
            for (int rr = 0; rr < 4; ++rr) {
                r0 = fmaf(relu(acc2[4 * rr + 0]), w3v[4 * rr + 0], r0);
                r1 = fmaf(relu(acc2[4 * rr + 1]), w3v[4 * rr + 1], r1);
                r2 = fmaf(relu(acc2[4 * rr + 2]), w3v[4 * rr + 2], r2);
                r3 = fmaf(relu(acc2[4 * rr + 3]), w3v[4 * rr + 3], r3);
            }
            float red = (r0 + r1) + (r2 + r3);
            red += __shfl_xor(red, 32);
            float o = 1.f / (1.f + __expf(-(red + b3s)));
            if (valid) *op = o;
            op += NI;
            ap += 32;
        }
    } else {
        // ---- user_sim
        int b = bx - 1252;
        if (t < D) nb[t] = ws[WS_N + b * D + t];
        __syncthreads();
        const float* nj = ws + WS_N + t * D;
        float acc = 0.f;
        #pragma unroll
        for (int d = 0; d < D; ++d) acc += nb[d] * nj[d];
        out[OUT_SIM + (long)b * 256 + t] = (1.f - acc) * 0.5f;
    }
}

extern "C" void kernel_launch(void* const* d_in, const int* in_sizes, int n_in,
                              void* d_out, int out_size, void* d_ws, size_t ws_size,
                              hipStream_t stream) {
    const int*   users = (const int*)d_in[0];
    const float* uemb  = (const float*)d_in[1];
    const float* iemb  = (const float*)d_in[2];
    const float *lw0 = (const float*)d_in[3],  *lb0 = (const float*)d_in[4];
    const float *lw1 = (const float*)d_in[5],  *lb1 = (const float*)d_in[6];
    const float *lw2 = (const float*)d_in[7],  *lb2 = (const float*)d_in[8];
    const float *lw3 = (const float*)d_in[9],  *lb3 = (const float*)d_in[10];
    const float *rw0 = (const float*)d_in[11], *rb0 = (const float*)d_in[12];
    const float *rw1 = (const float*)d_in[13], *rb1 = (const float*)d_in[14];
    const float *rw2 = (const float*)d_in[15], *rb2 = (const float*)d_in[16];
    const float *rw3 = (const float*)d_in[17], *rb3 = (const float*)d_in[18];
    const float *pw0 = (const float*)d_in[19], *pb0 = (const float*)d_in[20];
    const float *pw1 = (const float*)d_in[21], *pb1 = (const float*)d_in[22];
    const float *pw2 = (const float*)d_in[23], *pb2 = (const float*)d_in[24];
    const float *pw3 = (const float*)d_in[25], *pb3 = (const float*)d_in[26];
    float* ws = (float*)d_ws;
    float* out = (float*)d_out;

    k_prep<<<1354, 256, 0, stream>>>(users, uemb, iemb, lw0, lb0, rw0, rb0,
                                     pw0, pb0, pw1, pb1, pw2, pb2, pw3, pb3,
                                     ws, out);
    k_main<<<1508, 256, 0, stream>>>(ws,
                                     lw1, lb1, lw2, lb2, lw3, lb3,
                                     rw1, rb1, rw2, rb2, rw3, rb3,
                                     out);
}

// Round 5
// 106.162 us; speedup vs baseline: 8.2913x; 1.1100x over previous
//
#include <hip/hip_runtime.h>
#include <hip/hip_bf16.h>

#define NB 256      // batch
#define D 64        // embedding dim
#define NI 10000    // items

typedef __attribute__((ext_vector_type(8))) short bf16x8;
typedef __attribute__((ext_vector_type(16))) float f32x16;

union PK8 { unsigned u[4]; bf16x8 v; };

// ws layout (float offsets)
static constexpr int WS_AL = 0;                   // A_l [256][32]
static constexpr int WS_AR = 8192;                // A_r [256][32]
static constexpr int WS_N  = 16384;               // n   [256][64]
static constexpr int WS_CL = 32768;               // C_l [10000][32]
static constexpr int WS_CR = 352768;              // C_r [10000][32]

// out layout (elements, f32)
static constexpr long OUT_LIKES = 0;
static constexpr long OUT_SIM   = 2560000;
static constexpr long OUT_RATED = 2625536;
static constexpr long OUT_POP   = 5185536;

// 2 f32 -> packed 2x bf16 (RNE)
__device__ __forceinline__ unsigned pkbf(float a, float b) {
    unsigned r;
    asm("v_cvt_pk_bf16_f32 %0, %1, %2" : "=v"(r) : "v"(a), "v"(b));
    return r;
}
__device__ __forceinline__ float relu(float x) { return fmaxf(x, 0.f); }

struct A4 { float4 a0, a1, a2, a3; };
__device__ __forceinline__ A4 ldA(const float* p) {
    A4 r;
    r.a0 = *(const float4*)p;        r.a1 = *(const float4*)(p + 4);
    r.a2 = *(const float4*)(p + 16); r.a3 = *(const float4*)(p + 20);
    return r;
}

// ================= prep: popular head | item C-proj | user gather+norm+A-proj
// (pop section FIRST in blockIdx order so its small 40-block tail isn't serialized last)
__global__ __launch_bounds__(256) void k_prep(
        const int* __restrict__ users, const float* __restrict__ uemb,
        const float* __restrict__ iemb,
        const float* __restrict__ lw0, const float* __restrict__ lb0,
        const float* __restrict__ rw0, const float* __restrict__ rb0,
        const float* __restrict__ pw0, const float* __restrict__ pb0,
        const float* __restrict__ pw1, const float* __restrict__ pb1,
        const float* __restrict__ pw2, const float* __restrict__ pb2,
        const float* __restrict__ pw3, const float* __restrict__ pb3,
        float* __restrict__ ws, float* __restrict__ out) {
    int bx = blockIdx.x, t = threadIdx.x;
    if (bx < 40) {
        // ---- popular = item_head(item_emb), one item per thread
        int gi = bx * 256 + t;
        if (gi >= NI) return;
        float h[32], hn[32];
        #pragma unroll
        for (int j = 0; j < 32; ++j) h[j] = pb0[j];
        const float4* xr = (const float4*)(iemb + (long)gi * D);
        #pragma unroll
        for (int d4 = 0; d4 < 16; ++d4) {
            float4 xv = xr[d4];
            float xa[4] = {xv.x, xv.y, xv.z, xv.w};
            #pragma unroll
            for (int q = 0; q < 4; ++q) {
                float x = xa[q]; int d = d4 * 4 + q;
                #pragma unroll
                for (int j4 = 0; j4 < 8; ++j4) {
                    float4 w = *(const float4*)&pw0[d * 32 + j4 * 4];
                    h[4*j4+0] += x * w.x; h[4*j4+1] += x * w.y;
                    h[4*j4+2] += x * w.z; h[4*j4+3] += x * w.w;
                }
            }
        }
        #pragma unroll
        for (int j = 0; j < 32; ++j) h[j] = fmaxf(h[j], 0.f);
        #pragma unroll
        for (int j = 0; j < 32; ++j) hn[j] = pb1[j];
        #pragma unroll
        for (int k = 0; k < 32; ++k) {
            float hk = h[k];
            #pragma unroll
            for (int j4 = 0; j4 < 8; ++j4) {
                float4 w = *(const float4*)&pw1[k * 32 + j4 * 4];
                hn[4*j4+0] += hk * w.x; hn[4*j4+1] += hk * w.y;
                hn[4*j4+2] += hk * w.z; hn[4*j4+3] += hk * w.w;
            }
        }
        #pragma unroll
        for (int j = 0; j < 32; ++j) h[j] = fmaxf(hn[j], 0.f);
        #pragma unroll
        for (int j = 0; j < 32; ++j) hn[j] = pb2[j];
        #pragma unroll
        for (int k = 0; k < 32; ++k) {
            float hk = h[k];
            #pragma unroll
            for (int j4 = 0; j4 < 8; ++j4) {
                float4 w = *(const float4*)&pw2[k * 32 + j4 * 4];
                hn[4*j4+0] += hk * w.x; hn[4*j4+1] += hk * w.y;
                hn[4*j4+2] += hk * w.z; hn[4*j4+3] += hk * w.w;
            }
        }
        float acc = pb3[0];
        #pragma unroll
        for (int j = 0; j < 32; ++j) acc += fmaxf(hn[j], 0.f) * pw3[j];
        out[OUT_POP + gi] = 1.f / (1.f + __expf(-acc));
    } else if (bx < 40 + 1250) {
        // ---- item projections C = ie @ W0[D:] for both heads
        int i0 = (bx - 40) * 8;
        __shared__ float xs[8][D];
        for (int idx = t; idx < 8 * D; idx += 256) {
            int it = idx >> 6, d = idx & 63; int gi = i0 + it;
            xs[it][d] = (gi < NI) ? iemb[(long)gi * D + d] : 0.f;
        }
        __syncthreads();
        int it = t >> 5, j = t & 31; int gi = i0 + it;
        float al = 0.f, ar = 0.f;
        #pragma unroll
        for (int d = 0; d < D; ++d) {
            float x = xs[it][d];
            al += x * lw0[(D + d) * 32 + j];
            ar += x * rw0[(D + d) * 32 + j];
        }
        if (gi < NI) { ws[WS_CL + gi * 32 + j] = al; ws[WS_CR + gi * 32 + j] = ar; }
    } else {
        // ---- user precompute: 4 users per block, one wave each
        __shared__ float es[4][D];
        int ug = t >> 6, tt = t & 63;
        int b = (bx - 1290) * 4 + ug;
        int u = users[b];
        float e = uemb[(long)u * D + tt];
        float s = e * e;
        #pragma unroll
        for (int off = 32; off; off >>= 1) s += __shfl_down(s, off);
        s = __shfl(s, 0);
        ws[WS_N + b * D + tt] = e * rsqrtf(fmaxf(s, 1e-12f));
        es[ug][tt] = e;
        __syncthreads();
        const float* W0 = (tt < 32) ? lw0 : rw0;
        const float* bb = (tt < 32) ? lb0 : rb0;
        int j = tt & 31;
        float acc = bb[j];
        #pragma unroll
        for (int d = 0; d < D; ++d) acc += es[ug][d] * W0[d * 32 + j];
        ws[((tt < 32) ? WS_AL : WS_AR) + b * 32 + j] = acc;
    }
}

// ================= main: MFMA pair heads (likes+rated) + user_sim
// 32x32x16 bf16, transposed: D = W^T @ X^T.
//   C/D layout (verified m74/m101): col = lane&31 (pair), row = (reg&3)+8*(reg>>2)+4*(lane>>5).
//   k conventions: L1 kappa1(i,hi,m) = 8*hi + i + 16*m  (contiguous float4 loads)
//                  L2/L3 kappa2(i,hi,m) = (i&3)+8*(i>>2)+4*hi+16*m (C/D feeds B in-lane)
//   Layer-3 dot as MFMA: A-rows all = w3 (every output row = the dot), C-in = b3 broadcast.
//   2-user interleaved unroll for ILP + A-prefetch: latency-bound fix (R4 post-mortem).
__global__ __launch_bounds__(256) void k_main(
        const float* __restrict__ ws,
        const float* __restrict__ lw1, const float* __restrict__ lb1,
        const float* __restrict__ lw2, const float* __restrict__ lb2,
        const float* __restrict__ lw3, const float* __restrict__ lb3,
        const float* __restrict__ rw1, const float* __restrict__ rb1,
        const float* __restrict__ rw2, const float* __restrict__ rb2,
        const float* __restrict__ rw3, const float* __restrict__ rb3,
        float* __restrict__ out) {
    __shared__ float nb[D];
    int bx = blockIdx.x, t = threadIdx.x;
    if (bx < 1252) {
        int head = bx & 1;
        int ug = (bx >> 1) & 1;
        int ib = bx >> 2;                 // [0, 313)
        int i0 = ib * 32;
        const float* W1 = head ? rw1 : lw1; const float* B1 = head ? rb1 : lb1;
        const float* W2 = head ? rw2 : lw2; const float* B2 = head ? rb2 : lb2;
        const float* w3 = head ? rw3 : lw3; const float* b3 = head ? rb3 : lb3;
        int a_off = head ? WS_AR : WS_AL;
        int c_off = head ? WS_CR : WS_CL;
        float* ob = out + (head ? OUT_RATED : OUT_LIKES);

        int lane = t & 63, wv = t >> 6;
        int pr = lane & 31, hi = lane >> 5;
        int u0 = ug * 128 + wv * 32;

        // ---- weight fragments (A operands = W^T)
        PK8 w1a, w1b, w2a, w2b, w3a, w3b;
        #pragma unroll
        for (int j = 0; j < 4; ++j) {
            int k0 = 8 * hi + 2 * j;
            w1a.u[j] = pkbf(W1[k0 * 32 + pr],        W1[(k0 + 1) * 32 + pr]);
            w1b.u[j] = pkbf(W1[(16 + k0) * 32 + pr], W1[(17 + k0) * 32 + pr]);
        }
        #pragma unroll
        for (int j = 0; j < 4; ++j) {
            int fa = ((2 * j) & 3) + 8 * ((2 * j) >> 2) + 4 * hi;
            int fb = ((2 * j + 1) & 3) + 8 * ((2 * j + 1) >> 2) + 4 * hi;
            w2a.u[j] = pkbf(W2[fa * 32 + pr],        W2[fb * 32 + pr]);
            w2b.u[j] = pkbf(W2[(fa + 16) * 32 + pr], W2[(fb + 16) * 32 + pr]);
            w3a.u[j] = pkbf(w3[fa],                  w3[fb]);
            w3b.u[j] = pkbf(w3[fa + 16],             w3[fb + 16]);
        }
        float b3s = b3[0];
        f32x16 binit1, binit2, binit3;
        #pragma unroll
        for (int r = 0; r < 16; ++r) {
            int f = (r & 3) + 8 * (r >> 2) + 4 * hi;
            binit1[r] = B1[f]; binit2[r] = B2[f]; binit3[r] = b3s;
        }

        // ---- item projection values (fixed per block): C[pr][k] in kappa1 slots
        int crow = i0 + pr; if (crow > NI - 1) crow = NI - 1;
        const float* cp = ws + c_off + (long)crow * 32 + 8 * hi;
        float4 c0 = *(const float4*)cp;
        float4 c1 = *(const float4*)(cp + 4);
        float4 c2 = *(const float4*)(cp + 16);
        float4 c3 = *(const float4*)(cp + 20);

        bool valid = (hi == 0) && (i0 + pr < NI);
        float* op = ob + (long)u0 * NI + i0 + pr;
        const float* ap = ws + a_off + 8 * hi + (long)u0 * 32;

        A4 aA = ldA(ap);
        A4 aB = ldA(ap + 32);

        for (int u = 0; u < 32; u += 2) {
            // ---- build X fragments for both users (independent chains)
            PK8 xA0, xA1, xB0, xB1;
            xA0.u[0] = pkbf(relu(aA.a0.x + c0.x), relu(aA.a0.y + c0.y));
            xA0.u[1] = pkbf(relu(aA.a0.z + c0.z), relu(aA.a0.w + c0.w));
            xA0.u[2] = pkbf(relu(aA.a1.x + c1.x), relu(aA.a1.y + c1.y));
            xA0.u[3] = pkbf(relu(aA.a1.z + c1.z), relu(aA.a1.w + c1.w));
            xA1.u[0] = pkbf(relu(aA.a2.x + c2.x), relu(aA.a2.y + c2.y));
            xA1.u[1] = pkbf(relu(aA.a2.z + c2.z), relu(aA.a2.w + c2.w));
            xA1.u[2] = pkbf(relu(aA.a3.x + c3.x), relu(aA.a3.y + c3.y));
            xA1.u[3] = pkbf(relu(aA.a3.z + c3.z), relu(aA.a3.w + c3.w));
            xB0.u[0] = pkbf(relu(aB.a0.x + c0.x), relu(aB.a0.y + c0.y));
            xB0.u[1] = pkbf(relu(aB.a0.z + c0.z), relu(aB.a0.w + c0.w));
            xB0.u[2] = pkbf(relu(aB.a1.x + c1.x), relu(aB.a1.y + c1.y));
            xB0.u[3] = pkbf(relu(aB.a1.z + c1.z), relu(aB.a1.w + c1.w));
            xB1.u[0] = pkbf(relu(aB.a2.x + c2.x), relu(aB.a2.y + c2.y));
            xB1.u[1] = pkbf(relu(aB.a2.z + c2.z), relu(aB.a2.w + c2.w));
            xB1.u[2] = pkbf(relu(aB.a3.x + c3.x), relu(aB.a3.y + c3.y));
            xB1.u[3] = pkbf(relu(aB.a3.z + c3.z), relu(aB.a3.w + c3.w));
            // ---- layer 1, both users (4 independent-chain MFMAs in flight)
            f32x16 accA = binit1;
            accA = __builtin_amdgcn_mfma_f32_32x32x16_bf16(w1a.v, xA0.v, accA, 0, 0, 0);
            f32x16 accB = binit1;
            accB = __builtin_amdgcn_mfma_f32_32x32x16_bf16(w1a.v, xB0.v, accB, 0, 0, 0);
            accA = __builtin_amdgcn_mfma_f32_32x32x16_bf16(w1b.v, xA1.v, accA, 0, 0, 0);
            accB = __builtin_amdgcn_mfma_f32_32x32x16_bf16(w1b.v, xB1.v, accB, 0, 0, 0);
            // ---- prefetch next user pair (latency hides under the MFMA chains)
            int un = (u < 30) ? (u + 2) : u;
            aA = ldA(ap + (long)un * 32);
            aB = ldA(ap + (long)(un + 1) * 32);
            // ---- relu+pack, layer 2
            PK8 hA0, hA1, hB0, hB1;
            #pragma unroll
            for (int j = 0; j < 4; ++j) {
                hA0.u[j] = pkbf(relu(accA[2 * j]),     relu(accA[2 * j + 1]));
                hA1.u[j] = pkbf(relu(accA[8 + 2 * j]), relu(accA[9 + 2 * j]));
                hB0.u[j] = pkbf(relu(accB[2 * j]),     relu(accB[2 * j + 1]));
                hB1.u[j] = pkbf(relu(accB[8 + 2 * j]), relu(accB[9 + 2 * j]));
            }
            f32x16 acc2A = binit2;
            acc2A = __builtin_amdgcn_mfma_f32_32x32x16_bf16(w2a.v, hA0.v, acc2A, 0, 0, 0);
            f32x16 acc2B = binit2;
            acc2B = __builtin_amdgcn_mfma_f32_32x32x16_bf16(w2a.v, hB0.v, acc2B, 0, 0, 0);
            acc2A = __builtin_amdgcn_mfma_f32_32x32x16_bf16(w2b.v, hA1.v, acc2A, 0, 0, 0);
            acc2B = __builtin_amdgcn_mfma_f32_32x32x16_bf16(w2b.v, hB1.v, acc2B, 0, 0, 0);
            // ---- relu+pack, layer-3 dot on MFMA (all output rows = the dot; C-in = b3)
            PK8 gA0, gA1, gB0, gB1;
            #pragma unroll
            for (int j = 0; j < 4; ++j) {
                gA0.u[j] = pkbf(relu(acc2A[2 * j]),     relu(acc2A[2 * j + 1]));
                gA1.u[j] = pkbf(relu(acc2A[8 + 2 * j]), relu(acc2A[9 + 2 * j]));
                gB0.u[j] = pkbf(relu(acc2B[2 * j]),     relu(acc2B[2 * j + 1]));
                gB1.u[j] = pkbf(relu(acc2B[8 + 2 * j]), relu(acc2B[9 + 2 * j]));
            }
            f32x16 acc3A = binit3;
            acc3A = __builtin_amdgcn_mfma_f32_32x32x16_bf16(w3a.v, gA0.v, acc3A, 0, 0, 0);
            f32x16 acc3B = binit3;
            acc3B = __builtin_amdgcn_mfma_f32_32x32x16_bf16(w3a.v, gB0.v, acc3B, 0, 0, 0);
            acc3A = __builtin_amdgcn_mfma_f32_32x32x16_bf16(w3b.v, gA1.v, acc3A, 0, 0, 0);
            acc3B = __builtin_amdgcn_mfma_f32_32x32x16_bf16(w3b.v, gB1.v, acc3B, 0, 0, 0);
            // ---- sigmoid + store
            float oA = 1.f / (1.f + __expf(-acc3A[0]));
            float oB = 1.f / (1.f + __expf(-acc3B[0]));
            if (valid) { op[0] = oA; op[NI] = oB; }
            op += 2 * NI;
        }
    } else {
        // ---- user_sim
        int b = bx - 1252;
        if (t < D) nb[t] = ws[WS_N + b * D + t];
        __syncthreads();
        const float* nj = ws + WS_N + t * D;
        float acc = 0.f;
        #pragma unroll
        for (int d = 0; d < D; ++d) acc += nb[d] * nj[d];
        out[OUT_SIM + (long)b * 256 + t] = (1.f - acc) * 0.5f;
    }
}

extern "C" void kernel_launch(void* const* d_in, const int* in_sizes, int n_in,
                              void* d_out, int out_size, void* d_ws, size_t ws_size,
                              hipStream_t stream) {
    const int*   users = (const int*)d_in[0];
    const float* uemb  = (const float*)d_in[1];
    const float* iemb  = (const float*)d_in[2];
    const float *lw0 = (const float*)d_in[3],  *lb0 = (const float*)d_in[4];
    const float *lw1 = (const float*)d_in[5],  *lb1 = (const float*)d_in[6];
    const float *lw2 = (const float*)d_in[7],  *lb2 = (const float*)d_in[8];
    const float *lw3 = (const float*)d_in[9],  *lb3 = (const float*)d_in[10];
    const float *rw0 = (const float*)d_in[11], *rb0 = (const float*)d_in[12];
    const float *rw1 = (const float*)d_in[13], *rb1 = (const float*)d_in[14];
    const float *rw2 = (const float*)d_in[15], *rb2 = (const float*)d_in[16];
    const float *rw3 = (const float*)d_in[17], *rb3 = (const float*)d_in[18];
    const float *pw0 = (const float*)d_in[19], *pb0 = (const float*)d_in[20];
    const float *pw1 = (const float*)d_in[21], *pb1 = (const float*)d_in[22];
    const float *pw2 = (const float*)d_in[23], *pb2 = (const float*)d_in[24];
    const float *pw3 = (const float*)d_in[25], *pb3 = (const float*)d_in[26];
    float* ws = (float*)d_ws;
    float* out = (float*)d_out;

    k_prep<<<1354, 256, 0, stream>>>(users, uemb, iemb, lw0, lb0, rw0, rb0,
                                     pw0, pb0, pw1, pb1, pw2, pb2, pw3, pb3,
                                     ws, out);
    k_main<<<1508, 256, 0, stream>>>(ws,
                                     lw1, lb1, lw2, lb2, lw3, lb3,
                                     rw1, rb1, rw2, rb2, rw3, rb3,
                                     out);
}

// Round 6
// 87.107 us; speedup vs baseline: 10.1050x; 1.2187x over previous
//
#include <hip/hip_runtime.h>
#include <hip/hip_bf16.h>

#define NB 256      // batch
#define D 64        // embedding dim
#define NI 10000    // items

typedef __attribute__((ext_vector_type(8))) short bf16x8;
typedef __attribute__((ext_vector_type(16))) float f32x16;

union PK8 { unsigned u[4]; bf16x8 v; };

// ws layout (float offsets)
static constexpr int WS_AL = 0;                   // A_l [256][32]
static constexpr int WS_AR = 8192;                // A_r [256][32]
static constexpr int WS_N  = 16384;               // n   [256][64]
static constexpr int WS_CL = 32768;               // C_l [10000][32]
static constexpr int WS_CR = 352768;              // C_r [10000][32]

// out layout (elements, f32)
static constexpr long OUT_LIKES = 0;
static constexpr long OUT_SIM   = 2560000;
static constexpr long OUT_RATED = 2625536;
static constexpr long OUT_POP   = 5185536;

// 2 f32 -> packed 2x bf16 (RNE)
__device__ __forceinline__ unsigned pkbf(float a, float b) {
    unsigned r;
    asm("v_cvt_pk_bf16_f32 %0, %1, %2" : "=v"(r) : "v"(a), "v"(b));
    return r;
}
__device__ __forceinline__ float relu(float x) { return fmaxf(x, 0.f); }

struct A4 { float4 a0, a1, a2, a3; };
__device__ __forceinline__ A4 ldA(const float* p) {
    A4 r;
    r.a0 = *(const float4*)p;        r.a1 = *(const float4*)(p + 4);
    r.a2 = *(const float4*)(p + 16); r.a3 = *(const float4*)(p + 20);
    return r;
}

// ================= prep: popular-head (MFMA) | item C-proj | user gather+norm+A-proj
__global__ __launch_bounds__(256) void k_prep(
        const int* __restrict__ users, const float* __restrict__ uemb,
        const float* __restrict__ iemb,
        const float* __restrict__ lw0, const float* __restrict__ lb0,
        const float* __restrict__ rw0, const float* __restrict__ rb0,
        const float* __restrict__ pw0, const float* __restrict__ pb0,
        const float* __restrict__ pw1, const float* __restrict__ pb1,
        const float* __restrict__ pw2, const float* __restrict__ pb2,
        const float* __restrict__ pw3, const float* __restrict__ pb3,
        float* __restrict__ ws, float* __restrict__ out) {
    int bx = blockIdx.x, t = threadIdx.x;
    if (bx < 79) {
        // ---- popular = item_head(item_emb) on MFMA: one wave = 32 items
        int wv = t >> 6, lane = t & 63;
        int w = bx * 4 + wv;                 // wave index
        if (w >= 313) return;
        int i0 = w * 32;
        int pr = lane & 31, hi = lane >> 5;
        int crow = i0 + pr; if (crow > NI - 1) crow = NI - 1;
        // x fragments: kappa1 chunks m: k = 16m + 8*hi + i
        const float4* xr = (const float4*)(iemb + (long)crow * D);
        PK8 xm[4], w0f[4];
        #pragma unroll
        for (int m = 0; m < 4; ++m) {
            float4 xa = xr[4 * m + 2 * hi];
            float4 xb = xr[4 * m + 2 * hi + 1];
            xm[m].u[0] = pkbf(xa.x, xa.y); xm[m].u[1] = pkbf(xa.z, xa.w);
            xm[m].u[2] = pkbf(xb.x, xb.y); xm[m].u[3] = pkbf(xb.z, xb.w);
            #pragma unroll
            for (int j = 0; j < 4; ++j) {
                int r0 = 16 * m + 8 * hi + 2 * j;
                w0f[m].u[j] = pkbf(pw0[r0 * 32 + pr], pw0[(r0 + 1) * 32 + pr]);
            }
        }
        // kappa2-row weight fragments for layers 1..3
        PK8 w1a, w1b, w2a, w2b, w3a, w3b;
        f32x16 b0i, b1i, b2i, b3i;
        #pragma unroll
        for (int j = 0; j < 4; ++j) {
            int fa = ((2 * j) & 3) + 8 * ((2 * j) >> 2) + 4 * hi;
            int fb = ((2 * j + 1) & 3) + 8 * ((2 * j + 1) >> 2) + 4 * hi;
            w1a.u[j] = pkbf(pw1[fa * 32 + pr],        pw1[fb * 32 + pr]);
            w1b.u[j] = pkbf(pw1[(fa + 16) * 32 + pr], pw1[(fb + 16) * 32 + pr]);
            w2a.u[j] = pkbf(pw2[fa * 32 + pr],        pw2[fb * 32 + pr]);
            w2b.u[j] = pkbf(pw2[(fa + 16) * 32 + pr], pw2[(fb + 16) * 32 + pr]);
            w3a.u[j] = pkbf(pw3[fa],                  pw3[fb]);
            w3b.u[j] = pkbf(pw3[fa + 16],             pw3[fb + 16]);
        }
        float b3s = pb3[0];
        #pragma unroll
        for (int r = 0; r < 16; ++r) {
            int f = (r & 3) + 8 * (r >> 2) + 4 * hi;
            b0i[r] = pb0[f]; b1i[r] = pb1[f]; b2i[r] = pb2[f]; b3i[r] = b3s;
        }
        // layer 0 (K=64)
        f32x16 acc = b0i;
        acc = __builtin_amdgcn_mfma_f32_32x32x16_bf16(w0f[0].v, xm[0].v, acc, 0, 0, 0);
        acc = __builtin_amdgcn_mfma_f32_32x32x16_bf16(w0f[1].v, xm[1].v, acc, 0, 0, 0);
        acc = __builtin_amdgcn_mfma_f32_32x32x16_bf16(w0f[2].v, xm[2].v, acc, 0, 0, 0);
        acc = __builtin_amdgcn_mfma_f32_32x32x16_bf16(w0f[3].v, xm[3].v, acc, 0, 0, 0);
        PK8 g0, g1;
        #pragma unroll
        for (int j = 0; j < 4; ++j) {
            g0.u[j] = pkbf(relu(acc[2 * j]),     relu(acc[2 * j + 1]));
            g1.u[j] = pkbf(relu(acc[8 + 2 * j]), relu(acc[9 + 2 * j]));
        }
        f32x16 a1 = b1i;
        a1 = __builtin_amdgcn_mfma_f32_32x32x16_bf16(w1a.v, g0.v, a1, 0, 0, 0);
        a1 = __builtin_amdgcn_mfma_f32_32x32x16_bf16(w1b.v, g1.v, a1, 0, 0, 0);
        #pragma unroll
        for (int j = 0; j < 4; ++j) {
            g0.u[j] = pkbf(relu(a1[2 * j]),     relu(a1[2 * j + 1]));
            g1.u[j] = pkbf(relu(a1[8 + 2 * j]), relu(a1[9 + 2 * j]));
        }
        f32x16 a2 = b2i;
        a2 = __builtin_amdgcn_mfma_f32_32x32x16_bf16(w2a.v, g0.v, a2, 0, 0, 0);
        a2 = __builtin_amdgcn_mfma_f32_32x32x16_bf16(w2b.v, g1.v, a2, 0, 0, 0);
        #pragma unroll
        for (int j = 0; j < 4; ++j) {
            g0.u[j] = pkbf(relu(a2[2 * j]),     relu(a2[2 * j + 1]));
            g1.u[j] = pkbf(relu(a2[8 + 2 * j]), relu(a2[9 + 2 * j]));
        }
        f32x16 a3 = b3i;
        a3 = __builtin_amdgcn_mfma_f32_32x32x16_bf16(w3a.v, g0.v, a3, 0, 0, 0);
        a3 = __builtin_amdgcn_mfma_f32_32x32x16_bf16(w3b.v, g1.v, a3, 0, 0, 0);
        float o = 1.f / (1.f + __expf(-a3[0]));
        if (hi == 0 && i0 + pr < NI) out[OUT_POP + i0 + pr] = o;
    } else if (bx < 79 + 1250) {
        // ---- item projections C = ie @ W0[D:] for both heads
        int i0 = (bx - 79) * 8;
        __shared__ float xs[8][D];
        for (int idx = t; idx < 8 * D; idx += 256) {
            int it = idx >> 6, d = idx & 63; int gi = i0 + it;
            xs[it][d] = (gi < NI) ? iemb[(long)gi * D + d] : 0.f;
        }
        __syncthreads();
        int it = t >> 5, j = t & 31; int gi = i0 + it;
        float al = 0.f, ar = 0.f;
        #pragma unroll
        for (int d = 0; d < D; ++d) {
            float x = xs[it][d];
            al += x * lw0[(D + d) * 32 + j];
            ar += x * rw0[(D + d) * 32 + j];
        }
        if (gi < NI) { ws[WS_CL + gi * 32 + j] = al; ws[WS_CR + gi * 32 + j] = ar; }
    } else {
        // ---- user precompute: 4 users per block, one wave each
        __shared__ float es[4][D];
        int ug = t >> 6, tt = t & 63;
        int b = (bx - 1329) * 4 + ug;
        int u = users[b];
        float e = uemb[(long)u * D + tt];
        float s = e * e;
        #pragma unroll
        for (int off = 32; off; off >>= 1) s += __shfl_down(s, off);
        s = __shfl(s, 0);
        ws[WS_N + b * D + tt] = e * rsqrtf(fmaxf(s, 1e-12f));
        es[ug][tt] = e;
        __syncthreads();
        const float* W0 = (tt < 32) ? lw0 : rw0;
        const float* bb = (tt < 32) ? lb0 : rb0;
        int j = tt & 31;
        float acc = bb[j];
        #pragma unroll
        for (int d = 0; d < D; ++d) acc += es[ug][d] * W0[d * 32 + j];
        ws[((tt < 32) ? WS_AL : WS_AR) + b * 32 + j] = acc;
    }
}

// ================= main: MFMA pair heads (likes+rated) + user_sim
// 32x32x16 bf16, transposed: D = W^T @ X^T.
//   C/D layout (verified m74/m101): col = lane&31 (pair), row = (reg&3)+8*(reg>>2)+4*(lane>>5).
//   k conventions: L1 kappa1 = 8*hi + i + 16*m ; L2/L3 kappa2 = (i&3)+8*(i>>2)+4*hi+16*m.
//   8 users/wave (4 iterations) -> 5008 pair blocks: occupancy/tail fix (R5 post-mortem:
//   VGPR=124 caps 4 waves/SIMD = 1024 block slots; fat 1252-block grid had ~39% tail waste).
__global__ __launch_bounds__(256) void k_main(
        const float* __restrict__ ws,
        const float* __restrict__ lw1, const float* __restrict__ lb1,
        const float* __restrict__ lw2, const float* __restrict__ lb2,
        const float* __restrict__ lw3, const float* __restrict__ lb3,
        const float* __restrict__ rw1, const float* __restrict__ rb1,
        const float* __restrict__ rw2, const float* __restrict__ rb2,
        const float* __restrict__ rw3, const float* __restrict__ rb3,
        float* __restrict__ out) {
    __shared__ float nb[D];
    int bx = blockIdx.x, t = threadIdx.x;
    if (bx < 5008) {
        int head = bx & 1;
        int ug = (bx >> 1) & 7;
        int ib = bx >> 4;                 // [0, 313)
        int i0 = ib * 32;
        const float* W1 = head ? rw1 : lw1; const float* B1 = head ? rb1 : lb1;
        const float* W2 = head ? rw2 : lw2; const float* B2 = head ? rb2 : lb2;
        const float* w3 = head ? rw3 : lw3; const float* b3 = head ? rb3 : lb3;
        int a_off = head ? WS_AR : WS_AL;
        int c_off = head ? WS_CR : WS_CL;
        float* ob = out + (head ? OUT_RATED : OUT_LIKES);

        int lane = t & 63, wv = t >> 6;
        int pr = lane & 31, hi = lane >> 5;
        int u0 = ug * 32 + wv * 8;

        // ---- weight fragments (A operands = W^T)
        PK8 w1a, w1b, w2a, w2b, w3a, w3b;
        #pragma unroll
        for (int j = 0; j < 4; ++j) {
            int k0 = 8 * hi + 2 * j;
            w1a.u[j] = pkbf(W1[k0 * 32 + pr],        W1[(k0 + 1) * 32 + pr]);
            w1b.u[j] = pkbf(W1[(16 + k0) * 32 + pr], W1[(17 + k0) * 32 + pr]);
        }
        #pragma unroll
        for (int j = 0; j < 4; ++j) {
            int fa = ((2 * j) & 3) + 8 * ((2 * j) >> 2) + 4 * hi;
            int fb = ((2 * j + 1) & 3) + 8 * ((2 * j + 1) >> 2) + 4 * hi;
            w2a.u[j] = pkbf(W2[fa * 32 + pr],        W2[fb * 32 + pr]);
            w2b.u[j] = pkbf(W2[(fa + 16) * 32 + pr], W2[(fb + 16) * 32 + pr]);
            w3a.u[j] = pkbf(w3[fa],                  w3[fb]);
            w3b.u[j] = pkbf(w3[fa + 16],             w3[fb + 16]);
        }
        float b3s = b3[0];
        f32x16 binit1, binit2, binit3;
        #pragma unroll
        for (int r = 0; r < 16; ++r) {
            int f = (r & 3) + 8 * (r >> 2) + 4 * hi;
            binit1[r] = B1[f]; binit2[r] = B2[f]; binit3[r] = b3s;
        }

        // ---- item projection values (fixed per block): C[pr][k] in kappa1 slots
        int crow = i0 + pr; if (crow > NI - 1) crow = NI - 1;
        const float* cp = ws + c_off + (long)crow * 32 + 8 * hi;
        float4 c0 = *(const float4*)cp;
        float4 c1 = *(const float4*)(cp + 4);
        float4 c2 = *(const float4*)(cp + 16);
        float4 c3 = *(const float4*)(cp + 20);

        bool valid = (hi == 0) && (i0 + pr < NI);
        float* op = ob + (long)u0 * NI + i0 + pr;
        const float* ap = ws + a_off + 8 * hi + (long)u0 * 32;

        A4 aA = ldA(ap);
        A4 aB = ldA(ap + 32);

        for (int u = 0; u < 8; u += 2) {
            // ---- build X fragments for both users (independent chains)
            PK8 xA0, xA1, xB0, xB1;
            xA0.u[0] = pkbf(relu(aA.a0.x + c0.x), relu(aA.a0.y + c0.y));
            xA0.u[1] = pkbf(relu(aA.a0.z + c0.z), relu(aA.a0.w + c0.w));
            xA0.u[2] = pkbf(relu(aA.a1.x + c1.x), relu(aA.a1.y + c1.y));
            xA0.u[3] = pkbf(relu(aA.a1.z + c1.z), relu(aA.a1.w + c1.w));
            xA1.u[0] = pkbf(relu(aA.a2.x + c2.x), relu(aA.a2.y + c2.y));
            xA1.u[1] = pkbf(relu(aA.a2.z + c2.z), relu(aA.a2.w + c2.w));
            xA1.u[2] = pkbf(relu(aA.a3.x + c3.x), relu(aA.a3.y + c3.y));
            xA1.u[3] = pkbf(relu(aA.a3.z + c3.z), relu(aA.a3.w + c3.w));
            xB0.u[0] = pkbf(relu(aB.a0.x + c0.x), relu(aB.a0.y + c0.y));
            xB0.u[1] = pkbf(relu(aB.a0.z + c0.z), relu(aB.a0.w + c0.w));
            xB0.u[2] = pkbf(relu(aB.a1.x + c1.x), relu(aB.a1.y + c1.y));
            xB0.u[3] = pkbf(relu(aB.a1.z + c1.z), relu(aB.a1.w + c1.w));
            xB1.u[0] = pkbf(relu(aB.a2.x + c2.x), relu(aB.a2.y + c2.y));
            xB1.u[1] = pkbf(relu(aB.a2.z + c2.z), relu(aB.a2.w + c2.w));
            xB1.u[2] = pkbf(relu(aB.a3.x + c3.x), relu(aB.a3.y + c3.y));
            xB1.u[3] = pkbf(relu(aB.a3.z + c3.z), relu(aB.a3.w + c3.w));
            // ---- layer 1, both users
            f32x16 accA = binit1;
            accA = __builtin_amdgcn_mfma_f32_32x32x16_bf16(w1a.v, xA0.v, accA, 0, 0, 0);
            f32x16 accB = binit1;
            accB = __builtin_amdgcn_mfma_f32_32x32x16_bf16(w1a.v, xB0.v, accB, 0, 0, 0);
            accA = __builtin_amdgcn_mfma_f32_32x32x16_bf16(w1b.v, xA1.v, accA, 0, 0, 0);
            accB = __builtin_amdgcn_mfma_f32_32x32x16_bf16(w1b.v, xB1.v, accB, 0, 0, 0);
            // ---- prefetch next user pair
            int un = (u < 6) ? (u + 2) : u;
            aA = ldA(ap + (long)un * 32);
            aB = ldA(ap + (long)(un + 1) * 32);
            // ---- relu+pack, layer 2
            PK8 hA0, hA1, hB0, hB1;
            #pragma unroll
            for (int j = 0; j < 4; ++j) {
                hA0.u[j] = pkbf(relu(accA[2 * j]),     relu(accA[2 * j + 1]));
                hA1.u[j] = pkbf(relu(accA[8 + 2 * j]), relu(accA[9 + 2 * j]));
                hB0.u[j] = pkbf(relu(accB[2 * j]),     relu(accB[2 * j + 1]));
                hB1.u[j] = pkbf(relu(accB[8 + 2 * j]), relu(accB[9 + 2 * j]));
            }
            f32x16 acc2A = binit2;
            acc2A = __builtin_amdgcn_mfma_f32_32x32x16_bf16(w2a.v, hA0.v, acc2A, 0, 0, 0);
            f32x16 acc2B = binit2;
            acc2B = __builtin_amdgcn_mfma_f32_32x32x16_bf16(w2a.v, hB0.v, acc2B, 0, 0, 0);
            acc2A = __builtin_amdgcn_mfma_f32_32x32x16_bf16(w2b.v, hA1.v, acc2A, 0, 0, 0);
            acc2B = __builtin_amdgcn_mfma_f32_32x32x16_bf16(w2b.v, hB1.v, acc2B, 0, 0, 0);
            // ---- relu+pack, layer-3 dot on MFMA
            PK8 gA0, gA1, gB0, gB1;
            #pragma unroll
            for (int j = 0; j < 4; ++j) {
                gA0.u[j] = pkbf(relu(acc2A[2 * j]),     relu(acc2A[2 * j + 1]));
                gA1.u[j] = pkbf(relu(acc2A[8 + 2 * j]), relu(acc2A[9 + 2 * j]));
                gB0.u[j] = pkbf(relu(acc2B[2 * j]),     relu(acc2B[2 * j + 1]));
                gB1.u[j] = pkbf(relu(acc2B[8 + 2 * j]), relu(acc2B[9 + 2 * j]));
            }
            f32x16 acc3A = binit3;
            acc3A = __builtin_amdgcn_mfma_f32_32x32x16_bf16(w3a.v, gA0.v, acc3A, 0, 0, 0);
            f32x16 acc3B = binit3;
            acc3B = __builtin_amdgcn_mfma_f32_32x32x16_bf16(w3a.v, gB0.v, acc3B, 0, 0, 0);
            acc3A = __builtin_amdgcn_mfma_f32_32x32x16_bf16(w3b.v, gA1.v, acc3A, 0, 0, 0);
            acc3B = __builtin_amdgcn_mfma_f32_32x32x16_bf16(w3b.v, gB1.v, acc3B, 0, 0, 0);
            // ---- sigmoid + store
            float oA = 1.f / (1.f + __expf(-acc3A[0]));
            float oB = 1.f / (1.f + __expf(-acc3B[0]));
            if (valid) { op[0] = oA; op[NI] = oB; }
            op += 2 * NI;
        }
    } else {
        // ---- user_sim (float4 dot)
        int b = bx - 5008;
        if (t < D) nb[t] = ws[WS_N + b * D + t];
        __syncthreads();
        const float4* nj = (const float4*)(ws + WS_N + t * D);
        float acc = 0.f;
        #pragma unroll
        for (int d4 = 0; d4 < 16; ++d4) {
            float4 v = nj[d4];
            acc += nb[4*d4+0] * v.x + nb[4*d4+1] * v.y
                 + nb[4*d4+2] * v.z + nb[4*d4+3] * v.w;
        }
        out[OUT_SIM + (long)b * 256 + t] = (1.f - acc) * 0.5f;
    }
}

extern "C" void kernel_launch(void* const* d_in, const int* in_sizes, int n_in,
                              void* d_out, int out_size, void* d_ws, size_t ws_size,
                              hipStream_t stream) {
    const int*   users = (const int*)d_in[0];
    const float* uemb  = (const float*)d_in[1];
    const float* iemb  = (const float*)d_in[2];
    const float *lw0 = (const float*)d_in[3],  *lb0 = (const float*)d_in[4];
    const float *lw1 = (const float*)d_in[5],  *lb1 = (const float*)d_in[6];
    const float *lw2 = (const float*)d_in[7],  *lb2 = (const float*)d_in[8];
    const float *lw3 = (const float*)d_in[9],  *lb3 = (const float*)d_in[10];
    const float *rw0 = (const float*)d_in[11], *rb0 = (const float*)d_in[12];
    const float *rw1 = (const float*)d_in[13], *rb1 = (const float*)d_in[14];
    const float *rw2 = (const float*)d_in[15], *rb2 = (const float*)d_in[16];
    const float *rw3 = (const float*)d_in[17], *rb3 = (const float*)d_in[18];
    const float *pw0 = (const float*)d_in[19], *pb0 = (const float*)d_in[20];
    const float *pw1 = (const float*)d_in[21], *pb1 = (const float*)d_in[22];
    const float *pw2 = (const float*)d_in[23], *pb2 = (const float*)d_in[24];
    const float *pw3 = (const float*)d_in[25], *pb3 = (const float*)d_in[26];
    float* ws = (float*)d_ws;
    float* out = (float*)d_out;

    k_prep<<<1393, 256, 0, stream>>>(users, uemb, iemb, lw0, lb0, rw0, rb0,
                                     pw0, pb0, pw1, pb1, pw2, pb2, pw3, pb3,
                                     ws, out);
    k_main<<<5264, 256, 0, stream>>>(ws,
                                     lw1, lb1, lw2, lb2, lw3, lb3,
                                     rw1, rb1, rw2, rb2, rw3, rb3,
                                     out);
}

// Round 7
// 80.112 us; speedup vs baseline: 10.9873x; 1.0873x over previous
//
#include <hip/hip_runtime.h>
#include <hip/hip_bf16.h>

#define NB 256      // batch
#define D 64        // embedding dim
#define NI 10000    // items

typedef __attribute__((ext_vector_type(8))) short bf16x8;
typedef __attribute__((ext_vector_type(16))) float f32x16;

union PK8 { unsigned u[4]; bf16x8 v; };

// ws layout (float offsets)
static constexpr int WS_AL  = 0;                  // A_l [256][32]
static constexpr int WS_AR  = 8192;               // A_r [256][32]
static constexpr int WS_N   = 16384;              // n   [256][64]
static constexpr int WS_CL  = 32768;              // C_l [10000][32]
static constexpr int WS_CR  = 352768;             // C_r [10000][32]
static constexpr int WS_TAB = 672768;             // packed weight tables, 2 x 3600 floats
// table per head (3600 floats): 14 groups of [64 lanes][4 words] (16B units),
//   g0..g5  = w1a,w1b,w2a,w2b,w3a,w3b  (PK8 fragment words, u32)
//   g6..g9  = binit1[0..15]            (f32)
//   g10..g13= binit2[0..15]            (f32)
//   [14*256] = b3 scalar

// out layout (elements, f32)
static constexpr long OUT_LIKES = 0;
static constexpr long OUT_SIM   = 2560000;
static constexpr long OUT_RATED = 2625536;
static constexpr long OUT_POP   = 5185536;

// 2 f32 -> packed 2x bf16 (RNE)
__device__ __forceinline__ unsigned pkbf(float a, float b) {
    unsigned r;
    asm("v_cvt_pk_bf16_f32 %0, %1, %2" : "=v"(r) : "v"(a), "v"(b));
    return r;
}
__device__ __forceinline__ float relu(float x) { return fmaxf(x, 0.f); }

struct A4 { float4 a0, a1, a2, a3; };
__device__ __forceinline__ A4 ldA(const float* p) {
    A4 r;
    r.a0 = *(const float4*)p;        r.a1 = *(const float4*)(p + 4);
    r.a2 = *(const float4*)(p + 16); r.a3 = *(const float4*)(p + 20);
    return r;
}

// ================= prep: weight-table builder | popular-head (MFMA) | item C-proj | users
__global__ __launch_bounds__(256) void k_prep(
        const int* __restrict__ users, const float* __restrict__ uemb,
        const float* __restrict__ iemb,
        const float* __restrict__ lw0, const float* __restrict__ lb0,
        const float* __restrict__ rw0, const float* __restrict__ rb0,
        const float* __restrict__ lw1, const float* __restrict__ lb1,
        const float* __restrict__ lw2, const float* __restrict__ lb2,
        const float* __restrict__ lw3, const float* __restrict__ lb3,
        const float* __restrict__ rw1, const float* __restrict__ rb1,
        const float* __restrict__ rw2, const float* __restrict__ rb2,
        const float* __restrict__ rw3, const float* __restrict__ rb3,
        const float* __restrict__ pw0, const float* __restrict__ pb0,
        const float* __restrict__ pw1, const float* __restrict__ pb1,
        const float* __restrict__ pw2, const float* __restrict__ pb2,
        const float* __restrict__ pw3, const float* __restrict__ pb3,
        float* __restrict__ ws, float* __restrict__ out) {
    int bx = blockIdx.x, t = threadIdx.x;
    if (bx == 0) {
        // ---- build per-lane packed fragment tables for both pair heads
        if (t >= 128) return;
        int head = t >> 6, lane = t & 63;
        int pr = lane & 31, hi = lane >> 5;
        const float* W1 = head ? rw1 : lw1; const float* B1 = head ? rb1 : lb1;
        const float* W2 = head ? rw2 : lw2; const float* B2 = head ? rb2 : lb2;
        const float* w3 = head ? rw3 : lw3; const float* b3 = head ? rb3 : lb3;
        PK8 w1a, w1b, w2a, w2b, w3a, w3b;
        #pragma unroll
        for (int j = 0; j < 4; ++j) {
            int k0 = 8 * hi + 2 * j;
            w1a.u[j] = pkbf(W1[k0 * 32 + pr],        W1[(k0 + 1) * 32 + pr]);
            w1b.u[j] = pkbf(W1[(16 + k0) * 32 + pr], W1[(17 + k0) * 32 + pr]);
            int fa = ((2 * j) & 3) + 8 * ((2 * j) >> 2) + 4 * hi;
            int fb = ((2 * j + 1) & 3) + 8 * ((2 * j + 1) >> 2) + 4 * hi;
            w2a.u[j] = pkbf(W2[fa * 32 + pr],        W2[fb * 32 + pr]);
            w2b.u[j] = pkbf(W2[(fa + 16) * 32 + pr], W2[(fb + 16) * 32 + pr]);
            w3a.u[j] = pkbf(w3[fa],                  w3[fb]);
            w3b.u[j] = pkbf(w3[fa + 16],             w3[fb + 16]);
        }
        float* base = ws + WS_TAB + head * 3600;
        ((uint4*)base)[0 * 64 + lane] = *(uint4*)&w1a;
        ((uint4*)base)[1 * 64 + lane] = *(uint4*)&w1b;
        ((uint4*)base)[2 * 64 + lane] = *(uint4*)&w2a;
        ((uint4*)base)[3 * 64 + lane] = *(uint4*)&w2b;
        ((uint4*)base)[4 * 64 + lane] = *(uint4*)&w3a;
        ((uint4*)base)[5 * 64 + lane] = *(uint4*)&w3b;
        #pragma unroll
        for (int q = 0; q < 4; ++q) {
            float4 v1, v2;
            #pragma unroll
            for (int e = 0; e < 4; ++e) {
                int r = 4 * q + e;
                int f = (r & 3) + 8 * (r >> 2) + 4 * hi;
                ((float*)&v1)[e] = B1[f];
                ((float*)&v2)[e] = B2[f];
            }
            ((float4*)base)[(6 + q) * 64 + lane]  = v1;
            ((float4*)base)[(10 + q) * 64 + lane] = v2;
        }
        if (lane == 0) base[14 * 256] = b3[0];
    } else if (bx < 80) {
        // ---- popular = item_head(item_emb) on MFMA: one wave = 32 items
        int wv = t >> 6, lane = t & 63;
        int w = (bx - 1) * 4 + wv;
        if (w >= 313) return;
        int i0 = w * 32;
        int pr = lane & 31, hi = lane >> 5;
        int crow = i0 + pr; if (crow > NI - 1) crow = NI - 1;
        const float4* xr = (const float4*)(iemb + (long)crow * D);
        PK8 xm[4], w0f[4];
        #pragma unroll
        for (int m = 0; m < 4; ++m) {
            float4 xa = xr[4 * m + 2 * hi];
            float4 xb = xr[4 * m + 2 * hi + 1];
            xm[m].u[0] = pkbf(xa.x, xa.y); xm[m].u[1] = pkbf(xa.z, xa.w);
            xm[m].u[2] = pkbf(xb.x, xb.y); xm[m].u[3] = pkbf(xb.z, xb.w);
            #pragma unroll
            for (int j = 0; j < 4; ++j) {
                int r0 = 16 * m + 8 * hi + 2 * j;
                w0f[m].u[j] = pkbf(pw0[r0 * 32 + pr], pw0[(r0 + 1) * 32 + pr]);
            }
        }
        PK8 w1a, w1b, w2a, w2b, w3a, w3b;
        f32x16 b0i, b1i, b2i, b3i;
        #pragma unroll
        for (int j = 0; j < 4; ++j) {
            int fa = ((2 * j) & 3) + 8 * ((2 * j) >> 2) + 4 * hi;
            int fb = ((2 * j + 1) & 3) + 8 * ((2 * j + 1) >> 2) + 4 * hi;
            w1a.u[j] = pkbf(pw1[fa * 32 + pr],        pw1[fb * 32 + pr]);
            w1b.u[j] = pkbf(pw1[(fa + 16) * 32 + pr], pw1[(fb + 16) * 32 + pr]);
            w2a.u[j] = pkbf(pw2[fa * 32 + pr],        pw2[fb * 32 + pr]);
            w2b.u[j] = pkbf(pw2[(fa + 16) * 32 + pr], pw2[(fb + 16) * 32 + pr]);
            w3a.u[j] = pkbf(pw3[fa],                  pw3[fb]);
            w3b.u[j] = pkbf(pw3[fa + 16],             pw3[fb + 16]);
        }
        float b3s = pb3[0];
        #pragma unroll
        for (int r = 0; r < 16; ++r) {
            int f = (r & 3) + 8 * (r >> 2) + 4 * hi;
            b0i[r] = pb0[f]; b1i[r] = pb1[f]; b2i[r] = pb2[f]; b3i[r] = b3s;
        }
        f32x16 acc = b0i;
        acc = __builtin_amdgcn_mfma_f32_32x32x16_bf16(w0f[0].v, xm[0].v, acc, 0, 0, 0);
        acc = __builtin_amdgcn_mfma_f32_32x32x16_bf16(w0f[1].v, xm[1].v, acc, 0, 0, 0);
        acc = __builtin_amdgcn_mfma_f32_32x32x16_bf16(w0f[2].v, xm[2].v, acc, 0, 0, 0);
        acc = __builtin_amdgcn_mfma_f32_32x32x16_bf16(w0f[3].v, xm[3].v, acc, 0, 0, 0);
        PK8 g0, g1;
        #pragma unroll
        for (int j = 0; j < 4; ++j) {
            g0.u[j] = pkbf(relu(acc[2 * j]),     relu(acc[2 * j + 1]));
            g1.u[j] = pkbf(relu(acc[8 + 2 * j]), relu(acc[9 + 2 * j]));
        }
        f32x16 a1 = b1i;
        a1 = __builtin_amdgcn_mfma_f32_32x32x16_bf16(w1a.v, g0.v, a1, 0, 0, 0);
        a1 = __builtin_amdgcn_mfma_f32_32x32x16_bf16(w1b.v, g1.v, a1, 0, 0, 0);
        #pragma unroll
        for (int j = 0; j < 4; ++j) {
            g0.u[j] = pkbf(relu(a1[2 * j]),     relu(a1[2 * j + 1]));
            g1.u[j] = pkbf(relu(a1[8 + 2 * j]), relu(a1[9 + 2 * j]));
        }
        f32x16 a2 = b2i;
        a2 = __builtin_amdgcn_mfma_f32_32x32x16_bf16(w2a.v, g0.v, a2, 0, 0, 0);
        a2 = __builtin_amdgcn_mfma_f32_32x32x16_bf16(w2b.v, g1.v, a2, 0, 0, 0);
        #pragma unroll
        for (int j = 0; j < 4; ++j) {
            g0.u[j] = pkbf(relu(a2[2 * j]),     relu(a2[2 * j + 1]));
            g1.u[j] = pkbf(relu(a2[8 + 2 * j]), relu(a2[9 + 2 * j]));
        }
        f32x16 a3 = b3i;
        a3 = __builtin_amdgcn_mfma_f32_32x32x16_bf16(w3a.v, g0.v, a3, 0, 0, 0);
        a3 = __builtin_amdgcn_mfma_f32_32x32x16_bf16(w3b.v, g1.v, a3, 0, 0, 0);
        float o = 1.f / (1.f + __expf(-a3[0]));
        if (hi == 0 && i0 + pr < NI) out[OUT_POP + i0 + pr] = o;
    } else if (bx < 80 + 1250) {
        // ---- item projections C = ie @ W0[D:] for both heads
        int i0 = (bx - 80) * 8;
        __shared__ float xs[8][D];
        for (int idx = t; idx < 8 * D; idx += 256) {
            int it = idx >> 6, d = idx & 63; int gi = i0 + it;
            xs[it][d] = (gi < NI) ? iemb[(long)gi * D + d] : 0.f;
        }
        __syncthreads();
        int it = t >> 5, j = t & 31; int gi = i0 + it;
        float al = 0.f, ar = 0.f;
        #pragma unroll
        for (int d = 0; d < D; ++d) {
            float x = xs[it][d];
            al += x * lw0[(D + d) * 32 + j];
            ar += x * rw0[(D + d) * 32 + j];
        }
        if (gi < NI) { ws[WS_CL + gi * 32 + j] = al; ws[WS_CR + gi * 32 + j] = ar; }
    } else {
        // ---- user precompute: 4 users per block, one wave each
        __shared__ float es[4][D];
        int ug = t >> 6, tt = t & 63;
        int b = (bx - 1330) * 4 + ug;
        int u = users[b];
        float e = uemb[(long)u * D + tt];
        float s = e * e;
        #pragma unroll
        for (int off = 32; off; off >>= 1) s += __shfl_down(s, off);
        s = __shfl(s, 0);
        ws[WS_N + b * D + tt] = e * rsqrtf(fmaxf(s, 1e-12f));
        es[ug][tt] = e;
        __syncthreads();
        const float* W0 = (tt < 32) ? lw0 : rw0;
        const float* bb = (tt < 32) ? lb0 : rb0;
        int j = tt & 31;
        float acc = bb[j];
        #pragma unroll
        for (int d = 0; d < D; ++d) acc += es[ug][d] * W0[d * 32 + j];
        ws[((tt < 32) ? WS_AL : WS_AR) + b * 32 + j] = acc;
    }
}

// ================= main: MFMA pair heads (likes+rated) + user_sim
// 32x32x16 bf16 transposed (D = W^T X^T); fragments/biases from the precomputed
// table (R7 fix: R6's ~100 scattered preamble loads + 60 pkbf -> 14 coalesced
// vector loads). 16 users/wave, 2-user-ILP loop; 2504 pair blocks.
__global__ __launch_bounds__(256) void k_main(
        const float* __restrict__ ws, float* __restrict__ out) {
    __shared__ float nb[D];
    int bx = blockIdx.x, t = threadIdx.x;
    if (bx < 2504) {
        int head = bx & 1;
        int ug = (bx >> 1) & 3;
        int ib = bx >> 3;                 // [0, 313)
        int i0 = ib * 32;
        int a_off = head ? WS_AR : WS_AL;
        int c_off = head ? WS_CR : WS_CL;
        float* ob = out + (head ? OUT_RATED : OUT_LIKES);

        int lane = t & 63, wv = t >> 6;
        int pr = lane & 31, hi = lane >> 5;
        int u0 = ug * 64 + wv * 16;

        // ---- load packed fragments/biases from table (coalesced 16B loads)
        const float* base = ws + WS_TAB + head * 3600;
        PK8 w1a, w1b, w2a, w2b, w3a, w3b;
        *(uint4*)&w1a = ((const uint4*)base)[0 * 64 + lane];
        *(uint4*)&w1b = ((const uint4*)base)[1 * 64 + lane];
        *(uint4*)&w2a = ((const uint4*)base)[2 * 64 + lane];
        *(uint4*)&w2b = ((const uint4*)base)[3 * 64 + lane];
        *(uint4*)&w3a = ((const uint4*)base)[4 * 64 + lane];
        *(uint4*)&w3b = ((const uint4*)base)[5 * 64 + lane];
        f32x16 binit1, binit2, binit3;
        #pragma unroll
        for (int q = 0; q < 4; ++q) {
            float4 v1 = ((const float4*)base)[(6 + q) * 64 + lane];
            float4 v2 = ((const float4*)base)[(10 + q) * 64 + lane];
            binit1[4*q+0] = v1.x; binit1[4*q+1] = v1.y;
            binit1[4*q+2] = v1.z; binit1[4*q+3] = v1.w;
            binit2[4*q+0] = v2.x; binit2[4*q+1] = v2.y;
            binit2[4*q+2] = v2.z; binit2[4*q+3] = v2.w;
        }
        float b3s = base[14 * 256];
        #pragma unroll
        for (int r = 0; r < 16; ++r) binit3[r] = b3s;

        // ---- item projection values (fixed per block): C[pr][k] in kappa1 slots
        int crow = i0 + pr; if (crow > NI - 1) crow = NI - 1;
        const float* cp = ws + c_off + (long)crow * 32 + 8 * hi;
        float4 c0 = *(const float4*)cp;
        float4 c1 = *(const float4*)(cp + 4);
        float4 c2 = *(const float4*)(cp + 16);
        float4 c3 = *(const float4*)(cp + 20);

        bool valid = (hi == 0) && (i0 + pr < NI);
        float* op = ob + (long)u0 * NI + i0 + pr;
        const float* ap = ws + a_off + 8 * hi + (long)u0 * 32;

        A4 aA = ldA(ap);
        A4 aB = ldA(ap + 32);

        for (int u = 0; u < 16; u += 2) {
            // ---- build X fragments for both users (independent chains)
            PK8 xA0, xA1, xB0, xB1;
            xA0.u[0] = pkbf(relu(aA.a0.x + c0.x), relu(aA.a0.y + c0.y));
            xA0.u[1] = pkbf(relu(aA.a0.z + c0.z), relu(aA.a0.w + c0.w));
            xA0.u[2] = pkbf(relu(aA.a1.x + c1.x), relu(aA.a1.y + c1.y));
            xA0.u[3] = pkbf(relu(aA.a1.z + c1.z), relu(aA.a1.w + c1.w));
            xA1.u[0] = pkbf(relu(aA.a2.x + c2.x), relu(aA.a2.y + c2.y));
            xA1.u[1] = pkbf(relu(aA.a2.z + c2.z), relu(aA.a2.w + c2.w));
            xA1.u[2] = pkbf(relu(aA.a3.x + c3.x), relu(aA.a3.y + c3.y));
            xA1.u[3] = pkbf(relu(aA.a3.z + c3.z), relu(aA.a3.w + c3.w));
            xB0.u[0] = pkbf(relu(aB.a0.x + c0.x), relu(aB.a0.y + c0.y));
            xB0.u[1] = pkbf(relu(aB.a0.z + c0.z), relu(aB.a0.w + c0.w));
            xB0.u[2] = pkbf(relu(aB.a1.x + c1.x), relu(aB.a1.y + c1.y));
            xB0.u[3] = pkbf(relu(aB.a1.z + c1.z), relu(aB.a1.w + c1.w));
            xB1.u[0] = pkbf(relu(aB.a2.x + c2.x), relu(aB.a2.y + c2.y));
            xB1.u[1] = pkbf(relu(aB.a2.z + c2.z), relu(aB.a2.w + c2.w));
            xB1.u[2] = pkbf(relu(aB.a3.x + c3.x), relu(aB.a3.y + c3.y));
            xB1.u[3] = pkbf(relu(aB.a3.z + c3.z), relu(aB.a3.w + c3.w));
            // ---- layer 1, both users
            f32x16 accA = binit1;
            accA = __builtin_amdgcn_mfma_f32_32x32x16_bf16(w1a.v, xA0.v, accA, 0, 0, 0);
            f32x16 accB = binit1;
            accB = __builtin_amdgcn_mfma_f32_32x32x16_bf16(w1a.v, xB0.v, accB, 0, 0, 0);
            accA = __builtin_amdgcn_mfma_f32_32x32x16_bf16(w1b.v, xA1.v, accA, 0, 0, 0);
            accB = __builtin_amdgcn_mfma_f32_32x32x16_bf16(w1b.v, xB1.v, accB, 0, 0, 0);
            // ---- prefetch next user pair
            int un = (u < 14) ? (u + 2) : u;
            aA = ldA(ap + (long)un * 32);
            aB = ldA(ap + (long)(un + 1) * 32);
            // ---- relu+pack, layer 2
            PK8 hA0, hA1, hB0, hB1;
            #pragma unroll
            for (int j = 0; j < 4; ++j) {
                hA0.u[j] = pkbf(relu(accA[2 * j]),     relu(accA[2 * j + 1]));
                hA1.u[j] = pkbf(relu(accA[8 + 2 * j]), relu(accA[9 + 2 * j]));
                hB0.u[j] = pkbf(relu(accB[2 * j]),     relu(accB[2 * j + 1]));
                hB1.u[j] = pkbf(relu(accB[8 + 2 * j]), relu(accB[9 + 2 * j]));
            }
            f32x16 acc2A = binit2;
            acc2A = __builtin_amdgcn_mfma_f32_32x32x16_bf16(w2a.v, hA0.v, acc2A, 0, 0, 0);
            f32x16 acc2B = binit2;
            acc2B = __builtin_amdgcn_mfma_f32_32x32x16_bf16(w2a.v, hB0.v, acc2B, 0, 0, 0);
            acc2A = __builtin_amdgcn_mfma_f32_32x32x16_bf16(w2b.v, hA1.v, acc2A, 0, 0, 0);
            acc2B = __builtin_amdgcn_mfma_f32_32x32x16_bf16(w2b.v, hB1.v, acc2B, 0, 0, 0);
            // ---- relu+pack, layer-3 dot on MFMA
            PK8 gA0, gA1, gB0, gB1;
            #pragma unroll
            for (int j = 0; j < 4; ++j) {
                gA0.u[j] = pkbf(relu(acc2A[2 * j]),     relu(acc2A[2 * j + 1]));
                gA1.u[j] = pkbf(relu(acc2A[8 + 2 * j]), relu(acc2A[9 + 2 * j]));
                gB0.u[j] = pkbf(relu(acc2B[2 * j]),     relu(acc2B[2 * j + 1]));
                gB1.u[j] = pkbf(relu(acc2B[8 + 2 * j]), relu(acc2B[9 + 2 * j]));
            }
            f32x16 acc3A = binit3;
            acc3A = __builtin_amdgcn_mfma_f32_32x32x16_bf16(w3a.v, gA0.v, acc3A, 0, 0, 0);
            f32x16 acc3B = binit3;
            acc3B = __builtin_amdgcn_mfma_f32_32x32x16_bf16(w3a.v, gB0.v, acc3B, 0, 0, 0);
            acc3A = __builtin_amdgcn_mfma_f32_32x32x16_bf16(w3b.v, gA1.v, acc3A, 0, 0, 0);
            acc3B = __builtin_amdgcn_mfma_f32_32x32x16_bf16(w3b.v, gB1.v, acc3B, 0, 0, 0);
            // ---- sigmoid + store
            float oA = 1.f / (1.f + __expf(-acc3A[0]));
            float oB = 1.f / (1.f + __expf(-acc3B[0]));
            if (valid) { op[0] = oA; op[NI] = oB; }
            op += 2 * NI;
        }
    } else {
        // ---- user_sim (float4 dot)
        int b = bx - 2504;
        if (t < D) nb[t] = ws[WS_N + b * D + t];
        __syncthreads();
        const float4* nj = (const float4*)(ws + WS_N + t * D);
        float acc = 0.f;
        #pragma unroll
        for (int d4 = 0; d4 < 16; ++d4) {
            float4 v = nj[d4];
            acc += nb[4*d4+0] * v.x + nb[4*d4+1] * v.y
                 + nb[4*d4+2] * v.z + nb[4*d4+3] * v.w;
        }
        out[OUT_SIM + (long)b * 256 + t] = (1.f - acc) * 0.5f;
    }
}

extern "C" void kernel_launch(void* const* d_in, const int* in_sizes, int n_in,
                              void* d_out, int out_size, void* d_ws, size_t ws_size,
                              hipStream_t stream) {
    const int*   users = (const int*)d_in[0];
    const float* uemb  = (const float*)d_in[1];
    const float* iemb  = (const float*)d_in[2];
    const float *lw0 = (const float*)d_in[3],  *lb0 = (const float*)d_in[4];
    const float *lw1 = (const float*)d_in[5],  *lb1 = (const float*)d_in[6];
    const float *lw2 = (const float*)d_in[7],  *lb2 = (const float*)d_in[8];
    const float *lw3 = (const float*)d_in[9],  *lb3 = (const float*)d_in[10];
    const float *rw0 = (const float*)d_in[11], *rb0 = (const float*)d_in[12];
    const float *rw1 = (const float*)d_in[13], *rb1 = (const float*)d_in[14];
    const float *rw2 = (const float*)d_in[15], *rb2 = (const float*)d_in[16];
    const float *rw3 = (const float*)d_in[17], *rb3 = (const float*)d_in[18];
    const float *pw0 = (const float*)d_in[19], *pb0 = (const float*)d_in[20];
    const float *pw1 = (const float*)d_in[21], *pb1 = (const float*)d_in[22];
    const float *pw2 = (const float*)d_in[23], *pb2 = (const float*)d_in[24];
    const float *pw3 = (const float*)d_in[25], *pb3 = (const float*)d_in[26];
    float* ws = (float*)d_ws;
    float* out = (float*)d_out;

    k_prep<<<1394, 256, 0, stream>>>(users, uemb, iemb,
                                     lw0, lb0, rw0, rb0,
                                     lw1, lb1, lw2, lb2, lw3, lb3,
                                     rw1, rb1, rw2, rb2, rw3, rb3,
                                     pw0, pb0, pw1, pb1, pw2, pb2, pw3, pb3,
                                     ws, out);
    k_main<<<2760, 256, 0, stream>>>(ws, out);
}

// Round 8
// 69.261 us; speedup vs baseline: 12.7086x; 1.1567x over previous
//
#include <hip/hip_runtime.h>
#include <hip/hip_bf16.h>

#define NB 256      // batch
#define D 64        // embedding dim
#define NI 10000    // items

typedef __attribute__((ext_vector_type(8))) short bf16x8;
typedef __attribute__((ext_vector_type(16))) float f32x16;

union PK8 { unsigned u[4]; bf16x8 v; };
union F16Q { f32x16 v; float4 q[4]; };

// ws layout (float offsets)
static constexpr int WS_AL  = 0;                  // A_l [256][32]
static constexpr int WS_AR  = 8192;               // A_r [256][32]
static constexpr int WS_N   = 16384;              // n   [256][64]
static constexpr int WS_CL  = 32768;              // C_l [10000][32]
static constexpr int WS_CR  = 352768;             // C_r [10000][32]
static constexpr int WS_TAB = 672768;             // packed weight tables, 2 x 4608 floats
// table per head (4608 floats = 18 groups of [64 lanes][4 words], 16B units):
//   g0..g5   = w1a,w1b,w2a,w2b,w3a,w3b  (PK8 fragment words, u32)
//   g6..g9   = binit1[0..15]            (f32)
//   g10..g13 = binit2[0..15]            (f32)
//   g14..g17 = b3 splat [0..15]         (f32)  -> L3 C-in includes bias

// out layout (elements, f32)
static constexpr long OUT_LIKES = 0;
static constexpr long OUT_SIM   = 2560000;
static constexpr long OUT_RATED = 2625536;
static constexpr long OUT_POP   = 5185536;

// 2 f32 -> packed 2x bf16 (RNE)
__device__ __forceinline__ unsigned pkbf(float a, float b) {
    unsigned r;
    asm("v_cvt_pk_bf16_f32 %0, %1, %2" : "=v"(r) : "v"(a), "v"(b));
    return r;
}
__device__ __forceinline__ float relu(float x) { return fmaxf(x, 0.f); }

struct A4 { float4 a0, a1, a2, a3; };
__device__ __forceinline__ A4 ldA(const float* p) {
    A4 r;
    r.a0 = *(const float4*)p;        r.a1 = *(const float4*)(p + 4);
    r.a2 = *(const float4*)(p + 16); r.a3 = *(const float4*)(p + 20);
    return r;
}

// ================= prep: weight-table builder | popular-head (MFMA) | item C-proj | users
__global__ __launch_bounds__(256) void k_prep(
        const int* __restrict__ users, const float* __restrict__ uemb,
        const float* __restrict__ iemb,
        const float* __restrict__ lw0, const float* __restrict__ lb0,
        const float* __restrict__ rw0, const float* __restrict__ rb0,
        const float* __restrict__ lw1, const float* __restrict__ lb1,
        const float* __restrict__ lw2, const float* __restrict__ lb2,
        const float* __restrict__ lw3, const float* __restrict__ lb3,
        const float* __restrict__ rw1, const float* __restrict__ rb1,
        const float* __restrict__ rw2, const float* __restrict__ rb2,
        const float* __restrict__ rw3, const float* __restrict__ rb3,
        const float* __restrict__ pw0, const float* __restrict__ pb0,
        const float* __restrict__ pw1, const float* __restrict__ pb1,
        const float* __restrict__ pw2, const float* __restrict__ pb2,
        const float* __restrict__ pw3, const float* __restrict__ pb3,
        float* __restrict__ ws, float* __restrict__ out) {
    int bx = blockIdx.x, t = threadIdx.x;
    if (bx == 0) {
        // ---- build per-lane packed fragment tables for both pair heads
        if (t >= 128) return;
        int head = t >> 6, lane = t & 63;
        int pr = lane & 31, hi = lane >> 5;
        const float* W1 = head ? rw1 : lw1; const float* B1 = head ? rb1 : lb1;
        const float* W2 = head ? rw2 : lw2; const float* B2 = head ? rb2 : lb2;
        const float* w3 = head ? rw3 : lw3; const float* b3 = head ? rb3 : lb3;
        PK8 w1a, w1b, w2a, w2b, w3a, w3b;
        #pragma unroll
        for (int j = 0; j < 4; ++j) {
            int k0 = 8 * hi + 2 * j;
            w1a.u[j] = pkbf(W1[k0 * 32 + pr],        W1[(k0 + 1) * 32 + pr]);
            w1b.u[j] = pkbf(W1[(16 + k0) * 32 + pr], W1[(17 + k0) * 32 + pr]);
            int fa = ((2 * j) & 3) + 8 * ((2 * j) >> 2) + 4 * hi;
            int fb = ((2 * j + 1) & 3) + 8 * ((2 * j + 1) >> 2) + 4 * hi;
            w2a.u[j] = pkbf(W2[fa * 32 + pr],        W2[fb * 32 + pr]);
            w2b.u[j] = pkbf(W2[(fa + 16) * 32 + pr], W2[(fb + 16) * 32 + pr]);
            w3a.u[j] = pkbf(w3[fa],                  w3[fb]);
            w3b.u[j] = pkbf(w3[fa + 16],             w3[fb + 16]);
        }
        float* base = ws + WS_TAB + head * 4608;
        ((uint4*)base)[0 * 64 + lane] = *(uint4*)&w1a;
        ((uint4*)base)[1 * 64 + lane] = *(uint4*)&w1b;
        ((uint4*)base)[2 * 64 + lane] = *(uint4*)&w2a;
        ((uint4*)base)[3 * 64 + lane] = *(uint4*)&w2b;
        ((uint4*)base)[4 * 64 + lane] = *(uint4*)&w3a;
        ((uint4*)base)[5 * 64 + lane] = *(uint4*)&w3b;
        #pragma unroll
        for (int q = 0; q < 4; ++q) {
            float4 v1, v2;
            #pragma unroll
            for (int e = 0; e < 4; ++e) {
                int r = 4 * q + e;
                int f = (r & 3) + 8 * (r >> 2) + 4 * hi;
                ((float*)&v1)[e] = B1[f];
                ((float*)&v2)[e] = B2[f];
            }
            ((float4*)base)[(6 + q) * 64 + lane]  = v1;
            ((float4*)base)[(10 + q) * 64 + lane] = v2;
        }
        float b3v = b3[0];
        float4 bs; bs.x = b3v; bs.y = b3v; bs.z = b3v; bs.w = b3v;
        #pragma unroll
        for (int q = 0; q < 4; ++q) ((float4*)base)[(14 + q) * 64 + lane] = bs;
    } else if (bx < 80) {
        // ---- popular = item_head(item_emb) on MFMA: one wave = 32 items
        int wv = t >> 6, lane = t & 63;
        int w = (bx - 1) * 4 + wv;
        if (w >= 313) return;
        int i0 = w * 32;
        int pr = lane & 31, hi = lane >> 5;
        int crow = i0 + pr; if (crow > NI - 1) crow = NI - 1;
        const float4* xr = (const float4*)(iemb + (long)crow * D);
        PK8 xm[4], w0f[4];
        #pragma unroll
        for (int m = 0; m < 4; ++m) {
            float4 xa = xr[4 * m + 2 * hi];
            float4 xb = xr[4 * m + 2 * hi + 1];
            xm[m].u[0] = pkbf(xa.x, xa.y); xm[m].u[1] = pkbf(xa.z, xa.w);
            xm[m].u[2] = pkbf(xb.x, xb.y); xm[m].u[3] = pkbf(xb.z, xb.w);
            #pragma unroll
            for (int j = 0; j < 4; ++j) {
                int r0 = 16 * m + 8 * hi + 2 * j;
                w0f[m].u[j] = pkbf(pw0[r0 * 32 + pr], pw0[(r0 + 1) * 32 + pr]);
            }
        }
        PK8 w1a, w1b, w2a, w2b, w3a, w3b;
        f32x16 b0i, b1i, b2i, b3i;
        #pragma unroll
        for (int j = 0; j < 4; ++j) {
            int fa = ((2 * j) & 3) + 8 * ((2 * j) >> 2) + 4 * hi;
            int fb = ((2 * j + 1) & 3) + 8 * ((2 * j + 1) >> 2) + 4 * hi;
            w1a.u[j] = pkbf(pw1[fa * 32 + pr],        pw1[fb * 32 + pr]);
            w1b.u[j] = pkbf(pw1[(fa + 16) * 32 + pr], pw1[(fb + 16) * 32 + pr]);
            w2a.u[j] = pkbf(pw2[fa * 32 + pr],        pw2[fb * 32 + pr]);
            w2b.u[j] = pkbf(pw2[(fa + 16) * 32 + pr], pw2[(fb + 16) * 32 + pr]);
            w3a.u[j] = pkbf(pw3[fa],                  pw3[fb]);
            w3b.u[j] = pkbf(pw3[fa + 16],             pw3[fb + 16]);
        }
        float b3s = pb3[0];
        #pragma unroll
        for (int r = 0; r < 16; ++r) {
            int f = (r & 3) + 8 * (r >> 2) + 4 * hi;
            b0i[r] = pb0[f]; b1i[r] = pb1[f]; b2i[r] = pb2[f]; b3i[r] = b3s;
        }
        f32x16 acc = b0i;
        acc = __builtin_amdgcn_mfma_f32_32x32x16_bf16(w0f[0].v, xm[0].v, acc, 0, 0, 0);
        acc = __builtin_amdgcn_mfma_f32_32x32x16_bf16(w0f[1].v, xm[1].v, acc, 0, 0, 0);
        acc = __builtin_amdgcn_mfma_f32_32x32x16_bf16(w0f[2].v, xm[2].v, acc, 0, 0, 0);
        acc = __builtin_amdgcn_mfma_f32_32x32x16_bf16(w0f[3].v, xm[3].v, acc, 0, 0, 0);
        PK8 g0, g1;
        #pragma unroll
        for (int j = 0; j < 4; ++j) {
            g0.u[j] = pkbf(relu(acc[2 * j]),     relu(acc[2 * j + 1]));
            g1.u[j] = pkbf(relu(acc[8 + 2 * j]), relu(acc[9 + 2 * j]));
        }
        f32x16 a1 = b1i;
        a1 = __builtin_amdgcn_mfma_f32_32x32x16_bf16(w1a.v, g0.v, a1, 0, 0, 0);
        a1 = __builtin_amdgcn_mfma_f32_32x32x16_bf16(w1b.v, g1.v, a1, 0, 0, 0);
        #pragma unroll
        for (int j = 0; j < 4; ++j) {
            g0.u[j] = pkbf(relu(a1[2 * j]),     relu(a1[2 * j + 1]));
            g1.u[j] = pkbf(relu(a1[8 + 2 * j]), relu(a1[9 + 2 * j]));
        }
        f32x16 a2 = b2i;
        a2 = __builtin_amdgcn_mfma_f32_32x32x16_bf16(w2a.v, g0.v, a2, 0, 0, 0);
        a2 = __builtin_amdgcn_mfma_f32_32x32x16_bf16(w2b.v, g1.v, a2, 0, 0, 0);
        #pragma unroll
        for (int j = 0; j < 4; ++j) {
            g0.u[j] = pkbf(relu(a2[2 * j]),     relu(a2[2 * j + 1]));
            g1.u[j] = pkbf(relu(a2[8 + 2 * j]), relu(a2[9 + 2 * j]));
        }
        f32x16 a3 = b3i;
        a3 = __builtin_amdgcn_mfma_f32_32x32x16_bf16(w3a.v, g0.v, a3, 0, 0, 0);
        a3 = __builtin_amdgcn_mfma_f32_32x32x16_bf16(w3b.v, g1.v, a3, 0, 0, 0);
        float o = 1.f / (1.f + __expf(-a3[0]));
        if (hi == 0 && i0 + pr < NI) out[OUT_POP + i0 + pr] = o;
    } else if (bx < 80 + 1250) {
        // ---- item projections C = ie @ W0[D:] for both heads
        int i0 = (bx - 80) * 8;
        __shared__ float xs[8][D];
        for (int idx = t; idx < 8 * D; idx += 256) {
            int it = idx >> 6, d = idx & 63; int gi = i0 + it;
            xs[it][d] = (gi < NI) ? iemb[(long)gi * D + d] : 0.f;
        }
        __syncthreads();
        int it = t >> 5, j = t & 31; int gi = i0 + it;
        float al = 0.f, ar = 0.f;
        #pragma unroll
        for (int d = 0; d < D; ++d) {
            float x = xs[it][d];
            al += x * lw0[(D + d) * 32 + j];
            ar += x * rw0[(D + d) * 32 + j];
        }
        if (gi < NI) { ws[WS_CL + gi * 32 + j] = al; ws[WS_CR + gi * 32 + j] = ar; }
    } else {
        // ---- user precompute: 4 users per block, one wave each
        __shared__ float es[4][D];
        int ug = t >> 6, tt = t & 63;
        int b = (bx - 1330) * 4 + ug;
        int u = users[b];
        float e = uemb[(long)u * D + tt];
        float s = e * e;
        #pragma unroll
        for (int off = 32; off; off >>= 1) s += __shfl_down(s, off);
        s = __shfl(s, 0);
        ws[WS_N + b * D + tt] = e * rsqrtf(fmaxf(s, 1e-12f));
        es[ug][tt] = e;
        __syncthreads();
        const float* W0 = (tt < 32) ? lw0 : rw0;
        const float* bb = (tt < 32) ? lb0 : rb0;
        int j = tt & 31;
        float acc = bb[j];
        #pragma unroll
        for (int d = 0; d < D; ++d) acc += es[ug][d] * W0[d * 32 + j];
        ws[((tt < 32) ? WS_AL : WS_AR) + b * 32 + j] = acc;
    }
}

// ================= main: MFMA pair heads (likes+rated) + user_sim
// R8: unified-VGPR diet (R7 post-mortem: 112 VGPR + 96 AGPR = ~208 unified ->
// 2 waves/SIMD cap was the 73-us invariant). Single-user chain; bias C-in
// tuples ds_read directly into accumulator unions (no persistent binit regs,
// no movs); b3 pre-splatted so L3 C-in includes it. Target <=128 unified ->
// 4 waves/SIMD, enforced by __launch_bounds__(256, 4).
__global__ __launch_bounds__(256, 4) void k_main(
        const float* __restrict__ ws, float* __restrict__ out) {
    __shared__ float tabf[4608];
    int bx = blockIdx.x, t = threadIdx.x;
    if (bx < 2504) {
        int head = bx & 1;
        int ug = (bx >> 1) & 3;
        int ib = bx >> 3;                 // [0, 313)
        int i0 = ib * 32;
        int a_off = head ? WS_AR : WS_AL;
        int c_off = head ? WS_CR : WS_CL;
        float* ob = out + (head ? OUT_RATED : OUT_LIKES);

        // ---- stage this head's table into LDS (1152 x float4, coalesced)
        {
            const float4* g = (const float4*)(ws + WS_TAB + head * 4608);
            float4* l = (float4*)tabf;
            for (int idx = t; idx < 1152; idx += 256) l[idx] = g[idx];
        }
        __syncthreads();

        int lane = t & 63, wv = t >> 6;
        int pr = lane & 31, hi = lane >> 5;
        int u0 = ug * 64 + wv * 16;

        const uint4*  tu = (const uint4*)tabf;
        const float4* tq = (const float4*)tabf;
        PK8 w1a, w1b, w2a, w2b, w3a, w3b;
        *(uint4*)&w1a = tu[0 * 64 + lane];
        *(uint4*)&w1b = tu[1 * 64 + lane];
        *(uint4*)&w2a = tu[2 * 64 + lane];
        *(uint4*)&w2b = tu[3 * 64 + lane];
        *(uint4*)&w3a = tu[4 * 64 + lane];
        *(uint4*)&w3b = tu[5 * 64 + lane];

        // ---- item projection values (fixed per block): C[pr][k] in kappa1 slots
        int crow = i0 + pr; if (crow > NI - 1) crow = NI - 1;
        const float* cp = ws + c_off + (long)crow * 32 + 8 * hi;
        float4 c0 = *(const float4*)cp;
        float4 c1 = *(const float4*)(cp + 4);
        float4 c2 = *(const float4*)(cp + 16);
        float4 c3 = *(const float4*)(cp + 20);

        bool valid = (hi == 0) && (i0 + pr < NI);
        float* op = ob + (long)u0 * NI + i0 + pr;
        const float* ap = ws + a_off + 8 * hi + (long)u0 * 32;

        A4 a = ldA(ap);
        for (int u = 0; u < 16; ++u) {
            A4 an = a;
            if (u < 15) an = ldA(ap + (long)(u + 1) * 32);   // prefetch next user
            // ---- X fragment: x[pr][k] = relu(A[b][k] + C[pr][k])
            PK8 x0, x1;
            x0.u[0] = pkbf(relu(a.a0.x + c0.x), relu(a.a0.y + c0.y));
            x0.u[1] = pkbf(relu(a.a0.z + c0.z), relu(a.a0.w + c0.w));
            x0.u[2] = pkbf(relu(a.a1.x + c1.x), relu(a.a1.y + c1.y));
            x0.u[3] = pkbf(relu(a.a1.z + c1.z), relu(a.a1.w + c1.w));
            x1.u[0] = pkbf(relu(a.a2.x + c2.x), relu(a.a2.y + c2.y));
            x1.u[1] = pkbf(relu(a.a2.z + c2.z), relu(a.a2.w + c2.w));
            x1.u[2] = pkbf(relu(a.a3.x + c3.x), relu(a.a3.y + c3.y));
            x1.u[3] = pkbf(relu(a.a3.z + c3.z), relu(a.a3.w + c3.w));
            // ---- layer 1 (bias C-in read straight from LDS into acc regs)
            F16Q acc;
            acc.q[0] = tq[6 * 64 + lane]; acc.q[1] = tq[7 * 64 + lane];
            acc.q[2] = tq[8 * 64 + lane]; acc.q[3] = tq[9 * 64 + lane];
            acc.v = __builtin_amdgcn_mfma_f32_32x32x16_bf16(w1a.v, x0.v, acc.v, 0, 0, 0);
            acc.v = __builtin_amdgcn_mfma_f32_32x32x16_bf16(w1b.v, x1.v, acc.v, 0, 0, 0);
            // ---- relu+pack, layer 2
            PK8 h0, h1;
            #pragma unroll
            for (int j = 0; j < 4; ++j) {
                h0.u[j] = pkbf(relu(acc.v[2 * j]),     relu(acc.v[2 * j + 1]));
                h1.u[j] = pkbf(relu(acc.v[8 + 2 * j]), relu(acc.v[9 + 2 * j]));
            }
            F16Q acc2;
            acc2.q[0] = tq[10 * 64 + lane]; acc2.q[1] = tq[11 * 64 + lane];
            acc2.q[2] = tq[12 * 64 + lane]; acc2.q[3] = tq[13 * 64 + lane];
            acc2.v = __builtin_amdgcn_mfma_f32_32x32x16_bf16(w2a.v, h0.v, acc2.v, 0, 0, 0);
            acc2.v = __builtin_amdgcn_mfma_f32_32x32x16_bf16(w2b.v, h1.v, acc2.v, 0, 0, 0);
            // ---- relu+pack, layer-3 dot on MFMA (C-in = b3 splat)
            PK8 g0, g1;
            #pragma unroll
            for (int j = 0; j < 4; ++j) {
                g0.u[j] = pkbf(relu(acc2.v[2 * j]),     relu(acc2.v[2 * j + 1]));
                g1.u[j] = pkbf(relu(acc2.v[8 + 2 * j]), relu(acc2.v[9 + 2 * j]));
            }
            F16Q acc3;
            acc3.q[0] = tq[14 * 64 + lane]; acc3.q[1] = tq[15 * 64 + lane];
            acc3.q[2] = tq[16 * 64 + lane]; acc3.q[3] = tq[17 * 64 + lane];
            acc3.v = __builtin_amdgcn_mfma_f32_32x32x16_bf16(w3a.v, g0.v, acc3.v, 0, 0, 0);
            acc3.v = __builtin_amdgcn_mfma_f32_32x32x16_bf16(w3b.v, g1.v, acc3.v, 0, 0, 0);
            // ---- sigmoid + store
            float o = 1.f / (1.f + __expf(-acc3.v[0]));
            if (valid) *op = o;
            op += NI;
            a = an;
        }
    } else {
        // ---- user_sim (float4 dot); reuse tabf[0..63] as the row cache
        int b = bx - 2504;
        if (t < D) tabf[t] = ws[WS_N + b * D + t];
        __syncthreads();
        const float4* nj = (const float4*)(ws + WS_N + t * D);
        float acc = 0.f;
        #pragma unroll
        for (int d4 = 0; d4 < 16; ++d4) {
            float4 v = nj[d4];
            acc += tabf[4*d4+0] * v.x + tabf[4*d4+1] * v.y
                 + tabf[4*d4+2] * v.z + tabf[4*d4+3] * v.w;
        }
        out[OUT_SIM + (long)b * 256 + t] = (1.f - acc) * 0.5f;
    }
}

extern "C" void kernel_launch(void* const* d_in, const int* in_sizes, int n_in,
                              void* d_out, int out_size, void* d_ws, size_t ws_size,
                              hipStream_t stream) {
    const int*   users = (const int*)d_in[0];
    const float* uemb  = (const float*)d_in[1];
    const float* iemb  = (const float*)d_in[2];
    const float *lw0 = (const float*)d_in[3],  *lb0 = (const float*)d_in[4];
    const float *lw1 = (const float*)d_in[5],  *lb1 = (const float*)d_in[6];
    const float *lw2 = (const float*)d_in[7],  *lb2 = (const float*)d_in[8];
    const float *lw3 = (const float*)d_in[9],  *lb3 = (const float*)d_in[10];
    const float *rw0 = (const float*)d_in[11], *rb0 = (const float*)d_in[12];
    const float *rw1 = (const float*)d_in[13], *rb1 = (const float*)d_in[14];
    const float *rw2 = (const float*)d_in[15], *rb2 = (const float*)d_in[16];
    const float *rw3 = (const float*)d_in[17], *rb3 = (const float*)d_in[18];
    const float *pw0 = (const float*)d_in[19], *pb0 = (const float*)d_in[20];
    const float *pw1 = (const float*)d_in[21], *pb1 = (const float*)d_in[22];
    const float *pw2 = (const float*)d_in[23], *pb2 = (const float*)d_in[24];
    const float *pw3 = (const float*)d_in[25], *pb3 = (const float*)d_in[26];
    float* ws = (float*)d_ws;
    float* out = (float*)d_out;

    k_prep<<<1394, 256, 0, stream>>>(users, uemb, iemb,
                                     lw0, lb0, rw0, rb0,
                                     lw1, lb1, lw2, lb2, lw3, lb3,
                                     rw1, rb1, rw2, rb2, rw3, rb3,
                                     pw0, pb0, pw1, pb1, pw2, pb2, pw3, pb3,
                                     ws, out);
    k_main<<<2760, 256, 0, stream>>>(ws, out);
}

// Round 10
// 65.739 us; speedup vs baseline: 13.3896x; 1.0536x over previous
//
#include <hip/hip_runtime.h>
#include <hip/hip_bf16.h>

#define NB 256      // batch
#define D 64        // embedding dim
#define NI 10000    // items

typedef __attribute__((ext_vector_type(8))) short bf16x8;
typedef __attribute__((ext_vector_type(16))) float f32x16;

union PK8 { unsigned u[4]; bf16x8 v; };
union F16Q { f32x16 v; float4 q[4]; };

// ws layout (float offsets)
static constexpr int WS_AL  = 0;                  // A_l [256][32]
static constexpr int WS_AR  = 8192;               // A_r [256][32]
static constexpr int WS_N   = 16384;              // n   [256][64]
static constexpr int WS_CL  = 32768;              // C_l [10000][32]
static constexpr int WS_CR  = 352768;             // C_r [10000][32]
static constexpr int WS_TAB = 672768;             // packed weight tables, 2 x 4608 floats
// table per head (4608 floats = 18 groups of [64 lanes][4 words], 16B units):
//   g0..g5   = w1a,w1b,w2a,w2b,w3a,w3b  (PK8 fragment words, u32)
//   g6..g9   = binit1[0..15]            (f32)
//   g10..g13 = binit2[0..15]            (f32)
//   g14..g17 = b3 splat [0..15]         (f32)  -> L3 C-in includes bias

// out layout (elements, f32)
static constexpr long OUT_LIKES = 0;
static constexpr long OUT_SIM   = 2560000;
static constexpr long OUT_RATED = 2625536;
static constexpr long OUT_POP   = 5185536;

// 2 f32 -> packed 2x bf16 (RNE)
__device__ __forceinline__ unsigned pkbf(float a, float b) {
    unsigned r;
    asm("v_cvt_pk_bf16_f32 %0, %1, %2" : "=v"(r) : "v"(a), "v"(b));
    return r;
}
__device__ __forceinline__ float relu(float x) { return fmaxf(x, 0.f); }

struct A4 { float4 a0, a1, a2, a3; };
__device__ __forceinline__ A4 ldA(const float* p) {
    A4 r;
    r.a0 = *(const float4*)p;        r.a1 = *(const float4*)(p + 4);
    r.a2 = *(const float4*)(p + 16); r.a3 = *(const float4*)(p + 20);
    return r;
}

// ================= prep: weight-table builder | popular-head (MFMA) | item C-proj | users
__global__ __launch_bounds__(256) void k_prep(
        const int* __restrict__ users, const float* __restrict__ uemb,
        const float* __restrict__ iemb,
        const float* __restrict__ lw0, const float* __restrict__ lb0,
        const float* __restrict__ rw0, const float* __restrict__ rb0,
        const float* __restrict__ lw1, const float* __restrict__ lb1,
        const float* __restrict__ lw2, const float* __restrict__ lb2,
        const float* __restrict__ lw3, const float* __restrict__ lb3,
        const float* __restrict__ rw1, const float* __restrict__ rb1,
        const float* __restrict__ rw2, const float* __restrict__ rb2,
        const float* __restrict__ rw3, const float* __restrict__ rb3,
        const float* __restrict__ pw0, const float* __restrict__ pb0,
        const float* __restrict__ pw1, const float* __restrict__ pb1,
        const float* __restrict__ pw2, const float* __restrict__ pb2,
        const float* __restrict__ pw3, const float* __restrict__ pb3,
        float* __restrict__ ws, float* __restrict__ out) {
    int bx = blockIdx.x, t = threadIdx.x;
    if (bx == 0) {
        // ---- build per-lane packed fragment tables for both pair heads
        if (t >= 128) return;
        int head = t >> 6, lane = t & 63;
        int pr = lane & 31, hi = lane >> 5;
        const float* W1 = head ? rw1 : lw1; const float* B1 = head ? rb1 : lb1;
        const float* W2 = head ? rw2 : lw2; const float* B2 = head ? rb2 : lb2;
        const float* w3 = head ? rw3 : lw3; const float* b3 = head ? rb3 : lb3;
        PK8 w1a, w1b, w2a, w2b, w3a, w3b;
        #pragma unroll
        for (int j = 0; j < 4; ++j) {
            int k0 = 8 * hi + 2 * j;
            w1a.u[j] = pkbf(W1[k0 * 32 + pr],        W1[(k0 + 1) * 32 + pr]);
            w1b.u[j] = pkbf(W1[(16 + k0) * 32 + pr], W1[(17 + k0) * 32 + pr]);
            int fa = ((2 * j) & 3) + 8 * ((2 * j) >> 2) + 4 * hi;
            int fb = ((2 * j + 1) & 3) + 8 * ((2 * j + 1) >> 2) + 4 * hi;
            w2a.u[j] = pkbf(W2[fa * 32 + pr],        W2[fb * 32 + pr]);
            w2b.u[j] = pkbf(W2[(fa + 16) * 32 + pr], W2[(fb + 16) * 32 + pr]);
            w3a.u[j] = pkbf(w3[fa],                  w3[fb]);
            w3b.u[j] = pkbf(w3[fa + 16],             w3[fb + 16]);
        }
        float* base = ws + WS_TAB + head * 4608;
        ((uint4*)base)[0 * 64 + lane] = *(uint4*)&w1a;
        ((uint4*)base)[1 * 64 + lane] = *(uint4*)&w1b;
        ((uint4*)base)[2 * 64 + lane] = *(uint4*)&w2a;
        ((uint4*)base)[3 * 64 + lane] = *(uint4*)&w2b;
        ((uint4*)base)[4 * 64 + lane] = *(uint4*)&w3a;
        ((uint4*)base)[5 * 64 + lane] = *(uint4*)&w3b;
        #pragma unroll
        for (int q = 0; q < 4; ++q) {
            float4 v1, v2;
            #pragma unroll
            for (int e = 0; e < 4; ++e) {
                int r = 4 * q + e;
                int f = (r & 3) + 8 * (r >> 2) + 4 * hi;
                ((float*)&v1)[e] = B1[f];
                ((float*)&v2)[e] = B2[f];
            }
            ((float4*)base)[(6 + q) * 64 + lane]  = v1;
            ((float4*)base)[(10 + q) * 64 + lane] = v2;
        }
        float b3v = b3[0];
        float4 bs; bs.x = b3v; bs.y = b3v; bs.z = b3v; bs.w = b3v;
        #pragma unroll
        for (int q = 0; q < 4; ++q) ((float4*)base)[(14 + q) * 64 + lane] = bs;
    } else if (bx < 80) {
        // ---- popular = item_head(item_emb) on MFMA: one wave = 32 items
        int wv = t >> 6, lane = t & 63;
        int w = (bx - 1) * 4 + wv;
        if (w >= 313) return;
        int i0 = w * 32;
        int pr = lane & 31, hi = lane >> 5;
        int crow = i0 + pr; if (crow > NI - 1) crow = NI - 1;
        const float4* xr = (const float4*)(iemb + (long)crow * D);
        PK8 xm[4], w0f[4];
        #pragma unroll
        for (int m = 0; m < 4; ++m) {
            float4 xa = xr[4 * m + 2 * hi];
            float4 xb = xr[4 * m + 2 * hi + 1];
            xm[m].u[0] = pkbf(xa.x, xa.y); xm[m].u[1] = pkbf(xa.z, xa.w);
            xm[m].u[2] = pkbf(xb.x, xb.y); xm[m].u[3] = pkbf(xb.z, xb.w);
            #pragma unroll
            for (int j = 0; j < 4; ++j) {
                int r0 = 16 * m + 8 * hi + 2 * j;
                w0f[m].u[j] = pkbf(pw0[r0 * 32 + pr], pw0[(r0 + 1) * 32 + pr]);
            }
        }
        PK8 w1a, w1b, w2a, w2b, w3a, w3b;
        f32x16 b0i, b1i, b2i, b3i;
        #pragma unroll
        for (int j = 0; j < 4; ++j) {
            int fa = ((2 * j) & 3) + 8 * ((2 * j) >> 2) + 4 * hi;
            int fb = ((2 * j + 1) & 3) + 8 * ((2 * j + 1) >> 2) + 4 * hi;
            w1a.u[j] = pkbf(pw1[fa * 32 + pr],        pw1[fb * 32 + pr]);
            w1b.u[j] = pkbf(pw1[(fa + 16) * 32 + pr], pw1[(fb + 16) * 32 + pr]);
            w2a.u[j] = pkbf(pw2[fa * 32 + pr],        pw2[fb * 32 + pr]);
            w2b.u[j] = pkbf(pw2[(fa + 16) * 32 + pr], pw2[(fb + 16) * 32 + pr]);
            w3a.u[j] = pkbf(pw3[fa],                  pw3[fb]);
            w3b.u[j] = pkbf(pw3[fa + 16],             pw3[fb + 16]);
        }
        float b3s = pb3[0];
        #pragma unroll
        for (int r = 0; r < 16; ++r) {
            int f = (r & 3) + 8 * (r >> 2) + 4 * hi;
            b0i[r] = pb0[f]; b1i[r] = pb1[f]; b2i[r] = pb2[f]; b3i[r] = b3s;
        }
        f32x16 acc = b0i;
        acc = __builtin_amdgcn_mfma_f32_32x32x16_bf16(w0f[0].v, xm[0].v, acc, 0, 0, 0);
        acc = __builtin_amdgcn_mfma_f32_32x32x16_bf16(w0f[1].v, xm[1].v, acc, 0, 0, 0);
        acc = __builtin_amdgcn_mfma_f32_32x32x16_bf16(w0f[2].v, xm[2].v, acc, 0, 0, 0);
        acc = __builtin_amdgcn_mfma_f32_32x32x16_bf16(w0f[3].v, xm[3].v, acc, 0, 0, 0);
        PK8 g0, g1;
        #pragma unroll
        for (int j = 0; j < 4; ++j) {
            g0.u[j] = pkbf(relu(acc[2 * j]),     relu(acc[2 * j + 1]));
            g1.u[j] = pkbf(relu(acc[8 + 2 * j]), relu(acc[9 + 2 * j]));
        }
        f32x16 a1 = b1i;
        a1 = __builtin_amdgcn_mfma_f32_32x32x16_bf16(w1a.v, g0.v, a1, 0, 0, 0);
        a1 = __builtin_amdgcn_mfma_f32_32x32x16_bf16(w1b.v, g1.v, a1, 0, 0, 0);
        #pragma unroll
        for (int j = 0; j < 4; ++j) {
            g0.u[j] = pkbf(relu(a1[2 * j]),     relu(a1[2 * j + 1]));
            g1.u[j] = pkbf(relu(a1[8 + 2 * j]), relu(a1[9 + 2 * j]));
        }
        f32x16 a2 = b2i;
        a2 = __builtin_amdgcn_mfma_f32_32x32x16_bf16(w2a.v, g0.v, a2, 0, 0, 0);
        a2 = __builtin_amdgcn_mfma_f32_32x32x16_bf16(w2b.v, g1.v, a2, 0, 0, 0);
        #pragma unroll
        for (int j = 0; j < 4; ++j) {
            g0.u[j] = pkbf(relu(a2[2 * j]),     relu(a2[2 * j + 1]));
            g1.u[j] = pkbf(relu(a2[8 + 2 * j]), relu(a2[9 + 2 * j]));
        }
        f32x16 a3 = b3i;
        a3 = __builtin_amdgcn_mfma_f32_32x32x16_bf16(w3a.v, g0.v, a3, 0, 0, 0);
        a3 = __builtin_amdgcn_mfma_f32_32x32x16_bf16(w3b.v, g1.v, a3, 0, 0, 0);
        float o = 1.f / (1.f + __expf(-a3[0]));
        if (hi == 0 && i0 + pr < NI) out[OUT_POP + i0 + pr] = o;
    } else if (bx < 80 + 1250) {
        // ---- item projections C = ie @ W0[D:] for both heads
        int i0 = (bx - 80) * 8;
        __shared__ float xs[8][D];
        for (int idx = t; idx < 8 * D; idx += 256) {
            int it = idx >> 6, d = idx & 63; int gi = i0 + it;
            xs[it][d] = (gi < NI) ? iemb[(long)gi * D + d] : 0.f;
        }
        __syncthreads();
        int it = t >> 5, j = t & 31; int gi = i0 + it;
        float al = 0.f, ar = 0.f;
        #pragma unroll
        for (int d = 0; d < D; ++d) {
            float x = xs[it][d];
            al += x * lw0[(D + d) * 32 + j];
            ar += x * rw0[(D + d) * 32 + j];
        }
        if (gi < NI) { ws[WS_CL + gi * 32 + j] = al; ws[WS_CR + gi * 32 + j] = ar; }
    } else {
        // ---- user precompute: 4 users per block, one wave each
        __shared__ float es[4][D];
        int ug = t >> 6, tt = t & 63;
        int b = (bx - 1330) * 4 + ug;
        int u = users[b];
        float e = uemb[(long)u * D + tt];
        float s = e * e;
        #pragma unroll
        for (int off = 32; off; off >>= 1) s += __shfl_down(s, off);
        s = __shfl(s, 0);
        ws[WS_N + b * D + tt] = e * rsqrtf(fmaxf(s, 1e-12f));
        es[ug][tt] = e;
        __syncthreads();
        const float* W0 = (tt < 32) ? lw0 : rw0;
        const float* bb = (tt < 32) ? lb0 : rb0;
        int j = tt & 31;
        float acc = bb[j];
        #pragma unroll
        for (int d = 0; d < D; ++d) acc += es[ug][d] * W0[d * 32 + j];
        ws[((tt < 32) ? WS_AL : WS_AR) + b * 32 + j] = acc;
    }
}

// ================= main: MFMA pair heads (likes+rated) + user_sim
// R10 = R8 structure + 2-user ILP (R9 post-mortem: latency-bound, both pipes
// ~80% idle; two independent chains interleave to halve effective chain/user;
// bias ds_reads shared by both users). Builtin MFMA (R9's inline-asm crashed).
// __launch_bounds__(256,3): ~170 unified regs, 3 waves/SIMD.
__global__ __launch_bounds__(256, 3) void k_main(
        const float* __restrict__ ws, float* __restrict__ out) {
    __shared__ float tabf[4608];
    int bx = blockIdx.x, t = threadIdx.x;
    if (bx < 2504) {
        int head = bx & 1;
        int ug = (bx >> 1) & 3;
        int ib = bx >> 3;                 // [0, 313)
        int i0 = ib * 32;
        int a_off = head ? WS_AR : WS_AL;
        int c_off = head ? WS_CR : WS_CL;
        float* ob = out + (head ? OUT_RATED : OUT_LIKES);

        // ---- stage this head's table into LDS (1152 x float4, coalesced)
        {
            const float4* g = (const float4*)(ws + WS_TAB + head * 4608);
            float4* l = (float4*)tabf;
            for (int idx = t; idx < 1152; idx += 256) l[idx] = g[idx];
        }
        __syncthreads();

        int lane = t & 63, wv = t >> 6;
        int pr = lane & 31, hi = lane >> 5;
        int u0 = ug * 64 + wv * 16;

        const uint4*  tu = (const uint4*)tabf;
        const float4* tq = (const float4*)tabf;
        PK8 w1a, w1b, w2a, w2b, w3a, w3b;
        *(uint4*)&w1a = tu[0 * 64 + lane];
        *(uint4*)&w1b = tu[1 * 64 + lane];
        *(uint4*)&w2a = tu[2 * 64 + lane];
        *(uint4*)&w2b = tu[3 * 64 + lane];
        *(uint4*)&w3a = tu[4 * 64 + lane];
        *(uint4*)&w3b = tu[5 * 64 + lane];

        // ---- item projection values (fixed per block): C[pr][k] in kappa1 slots
        int crow = i0 + pr; if (crow > NI - 1) crow = NI - 1;
        const float* cp = ws + c_off + (long)crow * 32 + 8 * hi;
        float4 c0 = *(const float4*)cp;
        float4 c1 = *(const float4*)(cp + 4);
        float4 c2 = *(const float4*)(cp + 16);
        float4 c3 = *(const float4*)(cp + 20);

        bool valid = (hi == 0) && (i0 + pr < NI);
        float* op = ob + (long)u0 * NI + i0 + pr;
        const float* ap = ws + a_off + 8 * hi + (long)u0 * 32;

        for (int u = 0; u < 16; u += 2) {
            A4 aA = ldA(ap + (long)u * 32);
            A4 aB = ldA(ap + (long)(u + 1) * 32);
            // ---- X fragments, both users (independent chains)
            PK8 xA0, xA1, xB0, xB1;
            xA0.u[0] = pkbf(relu(aA.a0.x + c0.x), relu(aA.a0.y + c0.y));
            xA0.u[1] = pkbf(relu(aA.a0.z + c0.z), relu(aA.a0.w + c0.w));
            xA0.u[2] = pkbf(relu(aA.a1.x + c1.x), relu(aA.a1.y + c1.y));
            xA0.u[3] = pkbf(relu(aA.a1.z + c1.z), relu(aA.a1.w + c1.w));
            xA1.u[0] = pkbf(relu(aA.a2.x + c2.x), relu(aA.a2.y + c2.y));
            xA1.u[1] = pkbf(relu(aA.a2.z + c2.z), relu(aA.a2.w + c2.w));
            xA1.u[2] = pkbf(relu(aA.a3.x + c3.x), relu(aA.a3.y + c3.y));
            xA1.u[3] = pkbf(relu(aA.a3.z + c3.z), relu(aA.a3.w + c3.w));
            xB0.u[0] = pkbf(relu(aB.a0.x + c0.x), relu(aB.a0.y + c0.y));
            xB0.u[1] = pkbf(relu(aB.a0.z + c0.z), relu(aB.a0.w + c0.w));
            xB0.u[2] = pkbf(relu(aB.a1.x + c1.x), relu(aB.a1.y + c1.y));
            xB0.u[3] = pkbf(relu(aB.a1.z + c1.z), relu(aB.a1.w + c1.w));
            xB1.u[0] = pkbf(relu(aB.a2.x + c2.x), relu(aB.a2.y + c2.y));
            xB1.u[1] = pkbf(relu(aB.a2.z + c2.z), relu(aB.a2.w + c2.w));
            xB1.u[2] = pkbf(relu(aB.a3.x + c3.x), relu(aB.a3.y + c3.y));
            xB1.u[3] = pkbf(relu(aB.a3.z + c3.z), relu(aB.a3.w + c3.w));
            // ---- layer 1 (bias C-in from LDS; one read pair feeds both users)
            F16Q accA, accB;
            accA.q[0] = tq[6 * 64 + lane]; accA.q[1] = tq[7 * 64 + lane];
            accA.q[2] = tq[8 * 64 + lane]; accA.q[3] = tq[9 * 64 + lane];
            accB = accA;
            accA.v = __builtin_amdgcn_mfma_f32_32x32x16_bf16(w1a.v, xA0.v, accA.v, 0, 0, 0);
            accB.v = __builtin_amdgcn_mfma_f32_32x32x16_bf16(w1a.v, xB0.v, accB.v, 0, 0, 0);
            accA.v = __builtin_amdgcn_mfma_f32_32x32x16_bf16(w1b.v, xA1.v, accA.v, 0, 0, 0);
            accB.v = __builtin_amdgcn_mfma_f32_32x32x16_bf16(w1b.v, xB1.v, accB.v, 0, 0, 0);
            // ---- relu+pack, layer 2
            PK8 hA0, hA1, hB0, hB1;
            #pragma unroll
            for (int j = 0; j < 4; ++j) {
                hA0.u[j] = pkbf(relu(accA.v[2 * j]),     relu(accA.v[2 * j + 1]));
                hA1.u[j] = pkbf(relu(accA.v[8 + 2 * j]), relu(accA.v[9 + 2 * j]));
                hB0.u[j] = pkbf(relu(accB.v[2 * j]),     relu(accB.v[2 * j + 1]));
                hB1.u[j] = pkbf(relu(accB.v[8 + 2 * j]), relu(accB.v[9 + 2 * j]));
            }
            F16Q acc2A, acc2B;
            acc2A.q[0] = tq[10 * 64 + lane]; acc2A.q[1] = tq[11 * 64 + lane];
            acc2A.q[2] = tq[12 * 64 + lane]; acc2A.q[3] = tq[13 * 64 + lane];
            acc2B = acc2A;
            acc2A.v = __builtin_amdgcn_mfma_f32_32x32x16_bf16(w2a.v, hA0.v, acc2A.v, 0, 0, 0);
            acc2B.v = __builtin_amdgcn_mfma_f32_32x32x16_bf16(w2a.v, hB0.v, acc2B.v, 0, 0, 0);
            acc2A.v = __builtin_amdgcn_mfma_f32_32x32x16_bf16(w2b.v, hA1.v, acc2A.v, 0, 0, 0);
            acc2B.v = __builtin_amdgcn_mfma_f32_32x32x16_bf16(w2b.v, hB1.v, acc2B.v, 0, 0, 0);
            // ---- relu+pack, layer-3 dot on MFMA (C-in = b3 splat)
            PK8 gA0, gA1, gB0, gB1;
            #pragma unroll
            for (int j = 0; j < 4; ++j) {
                gA0.u[j] = pkbf(relu(acc2A.v[2 * j]),     relu(acc2A.v[2 * j + 1]));
                gA1.u[j] = pkbf(relu(acc2A.v[8 + 2 * j]), relu(acc2A.v[9 + 2 * j]));
                gB0.u[j] = pkbf(relu(acc2B.v[2 * j]),     relu(acc2B.v[2 * j + 1]));
                gB1.u[j] = pkbf(relu(acc2B.v[8 + 2 * j]), relu(acc2B.v[9 + 2 * j]));
            }
            F16Q acc3A, acc3B;
            acc3A.q[0] = tq[14 * 64 + lane]; acc3A.q[1] = tq[15 * 64 + lane];
            acc3A.q[2] = tq[16 * 64 + lane]; acc3A.q[3] = tq[17 * 64 + lane];
            acc3B = acc3A;
            acc3A.v = __builtin_amdgcn_mfma_f32_32x32x16_bf16(w3a.v, gA0.v, acc3A.v, 0, 0, 0);
            acc3B.v = __builtin_amdgcn_mfma_f32_32x32x16_bf16(w3a.v, gB0.v, acc3B.v, 0, 0, 0);
            acc3A.v = __builtin_amdgcn_mfma_f32_32x32x16_bf16(w3b.v, gA1.v, acc3A.v, 0, 0, 0);
            acc3B.v = __builtin_amdgcn_mfma_f32_32x32x16_bf16(w3b.v, gB1.v, acc3B.v, 0, 0, 0);
            // ---- sigmoid + store
            float oA = 1.f / (1.f + __expf(-acc3A.v[0]));
            float oB = 1.f / (1.f + __expf(-acc3B.v[0]));
            if (valid) { op[0] = oA; op[NI] = oB; }
            op += 2 * NI;
        }
    } else {
        // ---- user_sim (float4 dot); reuse tabf[0..63] as the row cache
        int b = bx - 2504;
        if (t < D) tabf[t] = ws[WS_N + b * D + t];
        __syncthreads();
        const float4* nj = (const float4*)(ws + WS_N + t * D);
        float acc = 0.f;
        #pragma unroll
        for (int d4 = 0; d4 < 16; ++d4) {
            float4 v = nj[d4];
            acc += tabf[4*d4+0] * v.x + tabf[4*d4+1] * v.y
                 + tabf[4*d4+2] * v.z + tabf[4*d4+3] * v.w;
        }
        out[OUT_SIM + (long)b * 256 + t] = (1.f - acc) * 0.5f;
    }
}

extern "C" void kernel_launch(void* const* d_in, const int* in_sizes, int n_in,
                              void* d_out, int out_size, void* d_ws, size_t ws_size,
                              hipStream_t stream) {
    const int*   users = (const int*)d_in[0];
    const float* uemb  = (const float*)d_in[1];
    const float* iemb  = (const float*)d_in[2];
    const float *lw0 = (const float*)d_in[3],  *lb0 = (const float*)d_in[4];
    const float *lw1 = (const float*)d_in[5],  *lb1 = (const float*)d_in[6];
    const float *lw2 = (const float*)d_in[7],  *lb2 = (const float*)d_in[8];
    const float *lw3 = (const float*)d_in[9],  *lb3 = (const float*)d_in[10];
    const float *rw0 = (const float*)d_in[11], *rb0 = (const float*)d_in[12];
    const float *rw1 = (const float*)d_in[13], *rb1 = (const float*)d_in[14];
    const float *rw2 = (const float*)d_in[15], *rb2 = (const float*)d_in[16];
    const float *rw3 = (const float*)d_in[17], *rb3 = (const float*)d_in[18];
    const float *pw0 = (const float*)d_in[19], *pb0 = (const float*)d_in[20];
    const float *pw1 = (const float*)d_in[21], *pb1 = (const float*)d_in[22];
    const float *pw2 = (const float*)d_in[23], *pb2 = (const float*)d_in[24];
    const float *pw3 = (const float*)d_in[25], *pb3 = (const float*)d_in[26];
    float* ws = (float*)d_ws;
    float* out = (float*)d_out;

    k_prep<<<1394, 256, 0, stream>>>(users, uemb, iemb,
                                     lw0, lb0, rw0, rb0,
                                     lw1, lb1, lw2, lb2, lw3, lb3,
                                     rw1, rb1, rw2, rb2, rw3, rb3,
                                     pw0, pb0, pw1, pb1, pw2, pb2, pw3, pb3,
                                     ws, out);
    k_main<<<2760, 256, 0, stream>>>(ws, out);
}